// Round 17
// baseline (375.431 us; speedup 1.0000x reference)
//
#include <hip/hip_runtime.h>
#include <hip/hip_bf16.h>
#include <math.h>

#define T_ 128
#define NE_ 64
#define NA_ 8
#define B_ 512
#define OBS_ 64
#define D_ 128
#define CH_ 128
#define VH_ 256
#define M_ (T_*B_)   // 65536

typedef __attribute__((ext_vector_type(8))) short bf16x8;
typedef __attribute__((ext_vector_type(8))) _Float16 f16x8;
typedef __attribute__((ext_vector_type(4))) float f32x4;

__device__ __forceinline__ float sigmoidf_(float x){ return 1.f/(1.f+__expf(-x)); }
__device__ __forceinline__ unsigned short f2bu(float v){
  __hip_bfloat16 b = __float2bfloat16(v);
  return __builtin_bit_cast(unsigned short, b);
}
__device__ __forceinline__ float bu2f(unsigned short u){
  return __builtin_bit_cast(float, (unsigned int)u << 16);
}
__device__ __forceinline__ unsigned short f2hu(float v){
  _Float16 h = (_Float16)v;
  return __builtin_bit_cast(unsigned short, h);
}
__device__ __forceinline__ float hu2f(unsigned short u){
  return (float)__builtin_bit_cast(_Float16, u);
}

// ---------------------------------------------------------------------------
// embgi (R12 config, 8 waves).
// ---------------------------------------------------------------------------
__global__ __launch_bounds__(512)
void embgi_k(const float* __restrict__ obs,
             const ushort* __restrict__ e1wT, const float* __restrict__ e1b,
             const ushort* __restrict__ e2wT, const float* __restrict__ e2b,
             const ushort* __restrict__ gWiT, const float* __restrict__ gbi,
             ushort* __restrict__ giH)
{
  __shared__ ushort S1[128*136];
  __shared__ ushort S2[128*136];
  const int tid  = threadIdx.x;
  const int lane = tid & 63, wave = tid >> 6;   // 8 waves
  const int wm = wave >> 1, wn = wave & 1;      // 4x2 decomp, 32x64/wave
  const int quad = lane >> 4, ln = lane & 15;
  const int m0 = blockIdx.x * 128;

  f32x4 acc[2][4];

  // stage obs (f32 -> f16) into S1, e1wT into S2
  #pragma unroll
  for (int i=0;i<4;i++){
    int c4 = tid + i*512;                 // 2048 float4 groups
    int m = c4 >> 4, kf = (c4 & 15) * 4;
    float4 v = *(const float4*)&obs[(size_t)(m0+m)*OBS_ + kf];
    ushort4 h; h.x=f2hu(v.x); h.y=f2hu(v.y); h.z=f2hu(v.z); h.w=f2hu(v.w);
    *(ushort4*)&S1[m*136 + kf] = h;
  }
  #pragma unroll
  for (int i=0;i<2;i++){
    int c8 = tid + i*512;                 // 1024 ushort8
    int n = c8 >> 3, kq = (c8 & 7)*8;
    *(uint4*)&S2[n*136 + kq] = *(const uint4*)&e1wT[(size_t)n*64 + kq];
  }
  __syncthreads();

  // GEMM1: emb1 = relu(obs @ e1w + e1b), K=64
  #pragma unroll
  for (int i=0;i<2;i++)
    #pragma unroll
    for (int j=0;j<4;j++)
      #pragma unroll
      for (int r=0;r<4;r++) acc[i][j][r] = 0.f;
  #pragma unroll
  for (int ks=0; ks<2; ks++){
    const int kq = ks*32 + quad*8;
    f16x8 af[2], bfv[4];
    #pragma unroll
    for (int mt=0;mt<2;mt++)
      af[mt] = *(const f16x8*)&S1[(wm*32 + mt*16 + ln)*136 + kq];
    #pragma unroll
    for (int nt=0;nt<4;nt++)
      bfv[nt] = *(const f16x8*)&S2[(wn*64 + nt*16 + ln)*136 + kq];
    #pragma unroll
    for (int mt=0;mt<2;mt++)
      #pragma unroll
      for (int nt=0;nt<4;nt++)
        acc[mt][nt] = __builtin_amdgcn_mfma_f32_16x16x32_f16(af[mt], bfv[nt], acc[mt][nt], 0,0,0);
  }
  __syncthreads();   // everyone done reading S1/S2

  // emb1 -> S1; stage e2wT -> S2
  #pragma unroll
  for (int mt=0;mt<2;mt++)
    #pragma unroll
    for (int r=0;r<4;r++){
      int rl = wm*32 + mt*16 + quad*4 + r;
      #pragma unroll
      for (int nt=0;nt<4;nt++){
        int cl = wn*64 + nt*16 + ln;
        S1[rl*136 + cl] = f2hu(fmaxf(acc[mt][nt][r] + e1b[cl], 0.f));
      }
    }
  #pragma unroll
  for (int i=0;i<4;i++){
    int c8 = tid + i*512;
    int n = c8 >> 4, kq = (c8 & 15)*8;
    *(uint4*)&S2[n*136 + kq] = *(const uint4*)&e2wT[(size_t)n*128 + kq];
  }
  __syncthreads();

  // GEMM2: emb2 = relu(emb1 @ e2w + e2b), K=128
  #pragma unroll
  for (int i=0;i<2;i++)
    #pragma unroll
    for (int j=0;j<4;j++)
      #pragma unroll
      for (int r=0;r<4;r++) acc[i][j][r] = 0.f;
  #pragma unroll
  for (int ks=0; ks<4; ks++){
    const int kq = ks*32 + quad*8;
    f16x8 af[2], bfv[4];
    #pragma unroll
    for (int mt=0;mt<2;mt++)
      af[mt] = *(const f16x8*)&S1[(wm*32 + mt*16 + ln)*136 + kq];
    #pragma unroll
    for (int nt=0;nt<4;nt++)
      bfv[nt] = *(const f16x8*)&S2[(wn*64 + nt*16 + ln)*136 + kq];
    #pragma unroll
    for (int mt=0;mt<2;mt++)
      #pragma unroll
      for (int nt=0;nt<4;nt++)
        acc[mt][nt] = __builtin_amdgcn_mfma_f32_16x16x32_f16(af[mt], bfv[nt], acc[mt][nt], 0,0,0);
  }
  __syncthreads();   // done reading emb1(S1) / e2w(S2)

  // emb2 -> S1
  #pragma unroll
  for (int mt=0;mt<2;mt++)
    #pragma unroll
    for (int r=0;r<4;r++){
      int rl = wm*32 + mt*16 + quad*4 + r;
      #pragma unroll
      for (int nt=0;nt<4;nt++){
        int cl = wn*64 + nt*16 + ln;
        S1[rl*136 + cl] = f2hu(fmaxf(acc[mt][nt][r] + e2b[cl], 0.f));
      }
    }

  // gi chunks: gi[:, c*128 .. c*128+127] = emb2 @ gWi_chunk + gbi  (no act)
  for (int c=0; c<3; c++){
    #pragma unroll
    for (int i=0;i<4;i++){
      int c8 = tid + i*512;
      int n = c8 >> 4, kq = (c8 & 15)*8;
      *(uint4*)&S2[n*136 + kq] = *(const uint4*)&gWiT[(size_t)(c*128+n)*128 + kq];
    }
    __syncthreads();
    #pragma unroll
    for (int i=0;i<2;i++)
      #pragma unroll
      for (int j=0;j<4;j++)
        #pragma unroll
        for (int r=0;r<4;r++) acc[i][j][r] = 0.f;
    #pragma unroll
    for (int ks=0; ks<4; ks++){
      const int kq = ks*32 + quad*8;
      f16x8 af[2], bfv[4];
      #pragma unroll
      for (int mt=0;mt<2;mt++)
        af[mt] = *(const f16x8*)&S1[(wm*32 + mt*16 + ln)*136 + kq];
      #pragma unroll
      for (int nt=0;nt<4;nt++)
        bfv[nt] = *(const f16x8*)&S2[(wn*64 + nt*16 + ln)*136 + kq];
      #pragma unroll
      for (int mt=0;mt<2;mt++)
        #pragma unroll
        for (int nt=0;nt<4;nt++)
          acc[mt][nt] = __builtin_amdgcn_mfma_f32_16x16x32_f16(af[mt], bfv[nt], acc[mt][nt], 0,0,0);
    }
    __syncthreads();   // done reading S2 before next chunk restage
    #pragma unroll
    for (int mt=0;mt<2;mt++)
      #pragma unroll
      for (int r=0;r<4;r++){
        int row = m0 + wm*32 + mt*16 + quad*4 + r;
        #pragma unroll
        for (int nt=0;nt<4;nt++){
          int cl = wn*64 + nt*16 + ln;
          giH[(size_t)row*384 + c*128 + cl] = f2hu(acc[mt][nt][r] + gbi[c*128 + cl]);
        }
      }
  }
}

// ---------------------------------------------------------------------------
// R17 postgru v6: ALL weight B-fragments direct from global/L2 (extends the
// R16-proven scoped pattern to dpre/update/v1/v2 — each phase has ONE weight
// stream + acc[2][4]; R13's spill culprit was the fused ai+aj dual-stream
// phase, kept split here). Bs deleted (LDS ~107 KB); 9 stage phases + ~9
// barriers gone. Falsifier: WRITE_SIZE >> 256 KB = spills -> revert to R16.
// ---------------------------------------------------------------------------
__global__ __launch_bounds__(512, 1)
void postgru_k(const __hip_bfloat16* __restrict__ Xe, const __hip_bfloat16* __restrict__ bcatT,
               const float* __restrict__ chb, const float* __restrict__ cow,
               const float* __restrict__ cob,
               const __hip_bfloat16* __restrict__ uhwT, const float* __restrict__ uhb,
               const __hip_bfloat16* __restrict__ uowT, const float* __restrict__ uob,
               const int* __restrict__ dones,
               const __hip_bfloat16* __restrict__ v1wT, const float* __restrict__ v1b,
               const __hip_bfloat16* __restrict__ v2wT, const float* __restrict__ v2b,
               const float* __restrict__ vow, const float* __restrict__ vob,
               float* __restrict__ values)
{
  __shared__ ushort S1[128*136];                  // Xe tile (updated in place)
  __shared__ alignas(16) ushort Pool[2*128*136];  // A: XcS+AI+AJ / B: V1[2]
  __shared__ alignas(16) float cbw[CH_], cww[CH_];
  __shared__ float Cs[4][NA_][NA_];
  __shared__ float SRed[128];
  const int tid  = threadIdx.x;
  const int lane = tid & 63, wave = tid >> 6;     // 8 waves
  const int wm = wave >> 1, wn = wave & 1;        // 4x2 GEMM decomp
  const int quad = lane >> 4, ln = lane & 15;
  const int m0 = blockIdx.x * 128;

  const ushort* bcat = (const ushort*)bcatT;
  const ushort* uhw  = (const ushort*)uhwT;
  const ushort* uow  = (const ushort*)uowT;
  const ushort* v1w  = (const ushort*)v1wT;
  const ushort* v2w  = (const ushort*)v2wT;

  // phase-A carve of Pool (16B-aligned; AI/AJ row stride 132 f32 = 528B)
  ushort* XcS = Pool;                                              // 34816 B
  float (*AI)[132] = (float(*)[132])(Pool + 128*136);              // 16896 B
  float (*AJ)[132] = (float(*)[132])((char*)(Pool + 128*136) + 16896);

  // stage Xe -> S1, coupling vectors
  #pragma unroll
  for (int i=0;i<4;i++){
    int c8 = tid + i*512;
    int m = c8 >> 4, kq = (c8 & 15)*8;
    *(uint4*)&S1[m*136 + kq] = *(const uint4*)((const ushort*)Xe + (size_t)(m0+m)*128 + kq);
  }
  if (tid < 128){ cbw[tid] = chb[tid]; cww[tid] = cow[tid]; }
  const float cob0 = cob[0];
  __syncthreads();

  for (int it=0; it<2; it++){
    // ---- coupling: 4 groups of 4 envs (32 rows); bcat direct from L2 ----
    for (int g=0; g<4; g++){
      const int r0 = g*32;
      const int wrow = wave >> 2;      // 0..1  (16-row slabs of the group)
      const int wcol = wave & 3;       // 0..3  (32-col slabs)

      // ai: B-frags direct from bcatT rows 0..127
      {
        f32x4 accc[2];
        #pragma unroll
        for (int nt=0;nt<2;nt++)
          #pragma unroll
          for (int r=0;r<4;r++) accc[nt][r] = 0.f;
        #pragma unroll
        for (int ks=0; ks<4; ks++){
          const int kq = ks*32 + quad*8;
          bf16x8 af = *(const bf16x8*)&S1[(r0 + wrow*16 + ln)*136 + kq];
          #pragma unroll
          for (int nt=0;nt<2;nt++){
            int n = wcol*32 + nt*16 + ln;
            bf16x8 bfv = *(const bf16x8*)&bcat[(size_t)n*128 + kq];
            accc[nt] = __builtin_amdgcn_mfma_f32_16x16x32_bf16(af, bfv, accc[nt], 0,0,0);
          }
        }
        #pragma unroll
        for (int nt=0;nt<2;nt++)
          #pragma unroll
          for (int r=0;r<4;r++)
            AI[wrow*16 + quad*4 + r][wcol*32 + nt*16 + ln] = accc[nt][r];
      }
      // aj: B-frags direct from bcatT rows 128..255
      {
        f32x4 accc[2];
        #pragma unroll
        for (int nt=0;nt<2;nt++)
          #pragma unroll
          for (int r=0;r<4;r++) accc[nt][r] = 0.f;
        #pragma unroll
        for (int ks=0; ks<4; ks++){
          const int kq = ks*32 + quad*8;
          bf16x8 af = *(const bf16x8*)&S1[(r0 + wrow*16 + ln)*136 + kq];
          #pragma unroll
          for (int nt=0;nt<2;nt++){
            int n = wcol*32 + nt*16 + ln;
            bf16x8 bfv = *(const bf16x8*)&bcat[(size_t)(128+n)*128 + kq];
            accc[nt] = __builtin_amdgcn_mfma_f32_16x16x32_bf16(af, bfv, accc[nt], 0,0,0);
          }
        }
        #pragma unroll
        for (int nt=0;nt<2;nt++)
          #pragma unroll
          for (int r=0;r<4;r++)
            AJ[wrow*16 + quad*4 + r][wcol*32 + nt*16 + ln] = accc[nt][r];
      }
      __syncthreads();   // AI/AJ visible

      // Ch + C: thread = env(2)|i(3)|jg(1)|hq(3); 4 pairs (i, jg*4+jj)
      {
        const int env = tid >> 7;
        const int i   = (tid >> 4) & 7;
        const int jg  = (tid >> 3) & 1;
        const int hq  = tid & 7;
        const float* aiR = &AI[env*8 + i][0];
        const float* aj0 = &AJ[env*8 + jg*4 + 0][0];
        const float* aj1 = &AJ[env*8 + jg*4 + 1][0];
        const float* aj2 = &AJ[env*8 + jg*4 + 2][0];
        const float* aj3 = &AJ[env*8 + jg*4 + 3][0];
        float s0=0.f, s1=0.f, s2=0.f, s3=0.f;
        #pragma unroll
        for (int t=0; t<4; t++){
          int h = (hq + t*8)*4;
          float4 a4 = *(const float4*)&aiR[h];
          float4 c4 = *(const float4*)&cbw[h];
          float4 w4 = *(const float4*)&cww[h];
          float px = a4.x + c4.x, py = a4.y + c4.y, pz = a4.z + c4.z, pw = a4.w + c4.w;
          float4 b0 = *(const float4*)&aj0[h];
          s0 += fmaxf(px+b0.x,0.f)*w4.x + fmaxf(py+b0.y,0.f)*w4.y
              + fmaxf(pz+b0.z,0.f)*w4.z + fmaxf(pw+b0.w,0.f)*w4.w;
          float4 b1 = *(const float4*)&aj1[h];
          s1 += fmaxf(px+b1.x,0.f)*w4.x + fmaxf(py+b1.y,0.f)*w4.y
              + fmaxf(pz+b1.z,0.f)*w4.z + fmaxf(pw+b1.w,0.f)*w4.w;
          float4 b2 = *(const float4*)&aj2[h];
          s2 += fmaxf(px+b2.x,0.f)*w4.x + fmaxf(py+b2.y,0.f)*w4.y
              + fmaxf(pz+b2.z,0.f)*w4.z + fmaxf(pw+b2.w,0.f)*w4.w;
          float4 b3 = *(const float4*)&aj3[h];
          s3 += fmaxf(px+b3.x,0.f)*w4.x + fmaxf(py+b3.y,0.f)*w4.y
              + fmaxf(pz+b3.z,0.f)*w4.z + fmaxf(pw+b3.w,0.f)*w4.w;
        }
        s0 += __shfl_xor(s0,1); s0 += __shfl_xor(s0,2); s0 += __shfl_xor(s0,4);
        s1 += __shfl_xor(s1,1); s1 += __shfl_xor(s1,2); s1 += __shfl_xor(s1,4);
        s2 += __shfl_xor(s2,1); s2 += __shfl_xor(s2,2); s2 += __shfl_xor(s2,4);
        s3 += __shfl_xor(s3,1); s3 += __shfl_xor(s3,2); s3 += __shfl_xor(s3,4);
        if (hq == 0){
          int j0 = jg*4;
          float c0 = sigmoidf_(s0 + cob0); Cs[env][i][j0+0] = (i==j0+0)?0.f:c0;
          float c1 = sigmoidf_(s1 + cob0); Cs[env][i][j0+1] = (i==j0+1)?0.f:c1;
          float c2 = sigmoidf_(s2 + cob0); Cs[env][i][j0+2] = (i==j0+2)?0.f:c2;
          float c3 = sigmoidf_(s3 + cob0); Cs[env][i][j0+3] = (i==j0+3)?0.f:c3;
        }
      }
      __syncthreads();   // Cs visible

      // ctx = C @ e  -> XcS rows r0..r0+31 (bf16)
      {
        const int lr = tid >> 4;             // 0..31
        const int env = lr >> 3, ii = lr & 7;
        const int c0 = (tid & 15) * 8;
        #pragma unroll
        for (int cc=0; cc<2; cc++){
          int d = c0 + cc*4;
          float a0=0.f, a1=0.f, a2=0.f, a3=0.f;
          #pragma unroll
          for (int j=0;j<NA_;j++){
            float c = Cs[env][ii][j];
            ushort4 e4 = *(const ushort4*)&S1[(r0 + env*8 + j)*136 + d];
            a0 = fmaf(c, bu2f(e4.x), a0);
            a1 = fmaf(c, bu2f(e4.y), a1);
            a2 = fmaf(c, bu2f(e4.z), a2);
            a3 = fmaf(c, bu2f(e4.w), a3);
          }
          ushort4 o; o.x=f2bu(a0); o.y=f2bu(a1); o.z=f2bu(a2); o.w=f2bu(a3);
          *(ushort4*)&XcS[(r0 + lr)*136 + d] = o;
        }
      }
      __syncthreads();   // XcS group rows done; AI/AJ reusable next group
    }

    // ---- dpre = relu([Xe|ctx] @ uhwT + uhb), K=256; B direct from uhw ----
    f32x4 acc[2][4];
    #pragma unroll
    for (int i=0;i<2;i++)
      #pragma unroll
      for (int j=0;j<4;j++)
        #pragma unroll
        for (int r=0;r<4;r++) acc[i][j][r] = 0.f;

    #pragma unroll
    for (int kc=0; kc<2; kc++){
      const ushort* Ab = kc ? XcS : S1;
      #pragma unroll
      for (int ks=0; ks<4; ks++){
        const int kq = ks*32 + quad*8;
        bf16x8 af[2], bfv[4];
        #pragma unroll
        for (int mt=0;mt<2;mt++)
          af[mt] = *(const bf16x8*)&Ab[(wm*32 + mt*16 + ln)*136 + kq];
        #pragma unroll
        for (int nt=0;nt<4;nt++){
          int n = wn*64 + nt*16 + ln;
          bfv[nt] = *(const bf16x8*)&uhw[(size_t)n*256 + kc*128 + kq];
        }
        #pragma unroll
        for (int mt=0;mt<2;mt++)
          #pragma unroll
          for (int nt=0;nt<4;nt++)
            acc[mt][nt] = __builtin_amdgcn_mfma_f32_16x16x32_bf16(af[mt], bfv[nt], acc[mt][nt], 0,0,0);
      }
    }
    __syncthreads();   // all XcS reads complete before overwrite

    // dpre epilogue -> XcS (ctx consumed)
    #pragma unroll
    for (int mt=0;mt<2;mt++)
      #pragma unroll
      for (int r=0;r<4;r++){
        int rl = wm*32 + mt*16 + quad*4 + r;
        #pragma unroll
        for (int nt=0;nt<4;nt++){
          int cl = wn*64 + nt*16 + ln;
          XcS[rl*136 + cl] = f2bu(fmaxf(acc[mt][nt][r] + uhb[cl], 0.f));
        }
      }
    __syncthreads();   // dpre visible

    // ---- update: Xe = (Xe + relu(dpre @ uowT + uob)) * alive, in LDS ----
    f32x4 acc2[2][4];
    #pragma unroll
    for (int i=0;i<2;i++)
      #pragma unroll
      for (int j=0;j<4;j++)
        #pragma unroll
        for (int r=0;r<4;r++) acc2[i][j][r] = 0.f;
    #pragma unroll
    for (int ks=0; ks<4; ks++){
      const int kq = ks*32 + quad*8;
      bf16x8 af[2], bfv[4];
      #pragma unroll
      for (int mt=0;mt<2;mt++)
        af[mt] = *(const bf16x8*)&XcS[(wm*32 + mt*16 + ln)*136 + kq];
      #pragma unroll
      for (int nt=0;nt<4;nt++){
        int n = wn*64 + nt*16 + ln;
        bfv[nt] = *(const bf16x8*)&uow[(size_t)n*128 + kq];
      }
      #pragma unroll
      for (int mt=0;mt<2;mt++)
        #pragma unroll
        for (int nt=0;nt<4;nt++)
          acc2[mt][nt] = __builtin_amdgcn_mfma_f32_16x16x32_bf16(af[mt], bfv[nt], acc2[mt][nt], 0,0,0);
    }
    #pragma unroll
    for (int mt=0;mt<2;mt++){
      #pragma unroll
      for (int r=0;r<4;r++){
        int rl = wm*32 + mt*16 + quad*4 + r;
        int row = m0 + rl;
        float al = (dones[row]!=0) ? 0.f : 1.f;
        #pragma unroll
        for (int nt=0;nt<4;nt++){
          int cl = wn*64 + nt*16 + ln;
          float v = fmaxf(acc2[mt][nt][r] + uob[cl], 0.f);
          v += bu2f(S1[rl*136 + cl]);
          v *= al;
          S1[rl*136 + cl] = f2bu(v);   // per-cell single owner
        }
      }
    }
    __syncthreads();   // new Xe visible for next iter / value head
  }

  // ================= value head (V1 overlays Pool) =================
  ushort* V1 = Pool;   // [2][128*136]; XcS/AI/AJ dead

  // phase 1: both v1 halves (read S1 + v1w direct; disjoint V1 writes,
  // no intermediate barrier needed)
  #pragma unroll
  for (int h=0; h<2; h++){
    f32x4 acc[2][4];
    #pragma unroll
    for (int i=0;i<2;i++)
      #pragma unroll
      for (int j=0;j<4;j++)
        #pragma unroll
        for (int r=0;r<4;r++) acc[i][j][r] = 0.f;
    #pragma unroll
    for (int ks=0; ks<4; ks++){
      const int kq = ks*32 + quad*8;
      bf16x8 af[2], bfv[4];
      #pragma unroll
      for (int mt=0;mt<2;mt++)
        af[mt] = *(const bf16x8*)&S1[(wm*32 + mt*16 + ln)*136 + kq];
      #pragma unroll
      for (int nt=0;nt<4;nt++){
        int n = wn*64 + nt*16 + ln;
        bfv[nt] = *(const bf16x8*)&v1w[(size_t)(h*128+n)*128 + kq];
      }
      #pragma unroll
      for (int mt=0;mt<2;mt++)
        #pragma unroll
        for (int nt=0;nt<4;nt++)
          acc[mt][nt] = __builtin_amdgcn_mfma_f32_16x16x32_bf16(af[mt], bfv[nt], acc[mt][nt], 0,0,0);
    }
    #pragma unroll
    for (int mt=0;mt<2;mt++)
      #pragma unroll
      for (int r=0;r<4;r++){
        int rl = wm*32 + mt*16 + quad*4 + r;
        #pragma unroll
        for (int nt=0;nt<4;nt++){
          int cl = wn*64 + nt*16 + ln;
          V1[h*128*136 + rl*136 + cl] = f2bu(fmaxf(acc[mt][nt][r] + v1b[h*128 + cl], 0.f));
        }
      }
  }
  __syncthreads();   // V1 visible

  // phase 2: v2 (K=256 from V1, B direct from v2w); dot with vow
  float s[2][4];
  #pragma unroll
  for (int mt=0;mt<2;mt++)
    #pragma unroll
    for (int r=0;r<4;r++) s[mt][r] = 0.f;

  for (int oc=0; oc<2; oc++){
    f32x4 acc[2][4];
    #pragma unroll
    for (int i=0;i<2;i++)
      #pragma unroll
      for (int j=0;j<4;j++)
        #pragma unroll
        for (int r=0;r<4;r++) acc[i][j][r] = 0.f;
    #pragma unroll
    for (int kh=0; kh<2; kh++){
      #pragma unroll
      for (int ks=0; ks<4; ks++){
        const int kq = ks*32 + quad*8;
        bf16x8 af[2], bfv[4];
        #pragma unroll
        for (int mt=0;mt<2;mt++)
          af[mt] = *(const bf16x8*)&V1[kh*128*136 + (wm*32 + mt*16 + ln)*136 + kq];
        #pragma unroll
        for (int nt=0;nt<4;nt++){
          int n = wn*64 + nt*16 + ln;
          bfv[nt] = *(const bf16x8*)&v2w[(size_t)(oc*128+n)*256 + kh*128 + kq];
        }
        #pragma unroll
        for (int mt=0;mt<2;mt++)
          #pragma unroll
          for (int nt=0;nt<4;nt++)
            acc[mt][nt] = __builtin_amdgcn_mfma_f32_16x16x32_bf16(af[mt], bfv[nt], acc[mt][nt], 0,0,0);
      }
    }
    float v2bv[4], voww[4];
    #pragma unroll
    for (int nt=0;nt<4;nt++){
      int col = oc*128 + wn*64 + nt*16 + ln;
      v2bv[nt] = v2b[col];
      voww[nt] = vow[col];
    }
    #pragma unroll
    for (int mt=0;mt<2;mt++)
      #pragma unroll
      for (int r=0;r<4;r++){
        float p = 0.f;
        #pragma unroll
        for (int nt=0;nt<4;nt++)
          p += fmaxf(acc[mt][nt][r] + v2bv[nt], 0.f) * voww[nt];
        s[mt][r] += p;
      }
  }

  #pragma unroll
  for (int off=1; off<16; off<<=1)
    #pragma unroll
    for (int mt=0;mt<2;mt++)
      #pragma unroll
      for (int r=0;r<4;r++)
        s[mt][r] += __shfl_xor(s[mt][r], off);
  // cross-wave (wn 0/1) reduce via LDS, direct store (no atomics/memset)
  if (ln == 0 && wn == 1){
    #pragma unroll
    for (int mt=0;mt<2;mt++)
      #pragma unroll
      for (int r=0;r<4;r++)
        SRed[wm*32 + mt*16 + quad*4 + r] = s[mt][r];
  }
  __syncthreads();
  if (ln == 0 && wn == 0){
    float vob0 = vob[0];
    #pragma unroll
    for (int mt=0;mt<2;mt++)
      #pragma unroll
      for (int r=0;r<4;r++){
        int rl = wm*32 + mt*16 + quad*4 + r;
        values[m0 + rl] = s[mt][r] + SRed[rl] + vob0;
      }
  }
}

// ---------------------------------------------------------------------------
// MFMA GRU v10 (best measured: 84.9us, round 3). Parked.
// ---------------------------------------------------------------------------
__global__ __launch_bounds__(512, 1)
void grum8_k(const ushort* __restrict__ gih, const float* __restrict__ hidden0,
             const int* __restrict__ dones, const float* __restrict__ gWh,
             const float* __restrict__ bhn, __hip_bfloat16* __restrict__ eb_out,
             float* __restrict__ hout)
{
  __shared__ ushort wstg[32*392];
  __shared__ ushort hb[2][16*136];
  __shared__ float  dnS[T_*4];
  const int tid  = threadIdx.x;
  const int lane = tid & 63, wave = tid >> 6;
  const int quad = lane >> 4, ln = lane & 15;
  const int r0   = blockIdx.x * 4;
  const int col  = wave*16 + ln;
  const int lnb  = ln & 12;

  dnS[tid] = (dones[(size_t)(tid>>2)*B_ + r0 + (tid&3)] != 0) ? 1.f : 0.f;
  const float bhnr = bhn[col];

  for (int i=tid; i<16*136; i+=512){ hb[0][i]=0; hb[1][i]=0; }

  f16x8 bf[3][4];
  #pragma unroll
  for (int kc=0; kc<4; kc++){
    for (int i=tid; i<32*384; i+=512){
      int kk = i/384, c = i - kk*384;
      wstg[kk*392 + c] = f2hu(gWh[(size_t)(kc*32+kk)*384 + c]);
    }
    __syncthreads();
    #pragma unroll
    for (int g=0; g<3; g++){
      int c = g*128 + col;
      ushort tmp[8];
      #pragma unroll
      for (int j=0;j<8;j++) tmp[j] = wstg[(quad*8+j)*392 + c];
      bf[g][kc] = *(const f16x8*)tmp;
    }
    __syncthreads();
  }

  float hc = hidden0[(size_t)(r0+quad)*D_ + col];
  if (dnS[quad] > 0.5f) hc = 0.f;
  hb[0][(quad*4)*136 + col] = f2hu(hc);
  __syncthreads();

  const ushort* gbase = gih + ((size_t)(r0+quad))*384;
  const size_t  gstep = (size_t)B_*384;

  float c_r, c_z, c_n;
  c_r = hu2f(gbase[col]); c_z = hu2f(gbase[col+128]); c_n = hu2f(gbase[col+256]);
  ushort aR,aZ,aN, bR,bZ,bN, cR,cZ,cN, dR,dZ,dN;
  { const ushort* gp = gbase + 1*gstep; aR = gp[col]; aZ = gp[col+128]; aN = gp[col+256]; }
  { const ushort* gp = gbase + 2*gstep; bR = gp[col]; bZ = gp[col+128]; bN = gp[col+256]; }
  { const ushort* gp = gbase + 3*gstep; cR = gp[col]; cZ = gp[col+128]; cN = gp[col+256]; }
  dR=0; dZ=0; dN=0;

  ushort pend_eu = 0;

#define GSTEP(t, IR,IZ,IN, OR,OZ,ON)                                          \
  {                                                                           \
    if ((t) > 0)                                                              \
      ((ushort*)eb_out)[((size_t)((t)-1)*B_ + r0+quad)*D_ + col] = pend_eu;   \
    { int tl = (t)+4; if (tl > T_-1) tl = T_-1;                               \
      const ushort* gp = gbase + (size_t)tl*gstep;                            \
      OR = gp[col]; OZ = gp[col+128]; ON = gp[col+256]; }                     \
    const ushort* hbuf = hb[(t)&1];                                           \
    f32x4 accA[3], accB[3];                                                   \
    _Pragma("unroll")                                                         \
    for (int g=0;g<3;g++){                                                    \
      _Pragma("unroll")                                                       \
      for (int r=0;r<4;r++){ accA[g][r]=0.f; accB[g][r]=0.f; }                \
    }                                                                         \
    _Pragma("unroll")                                                         \
    for (int ks=0; ks<2; ks++){                                               \
      f16x8 ahA = *(const f16x8*)&hbuf[lnb*136 + (2*ks  )*32 + quad*8];       \
      f16x8 ahB = *(const f16x8*)&hbuf[lnb*136 + (2*ks+1)*32 + quad*8];       \
      _Pragma("unroll")                                                       \
      for (int g=0;g<3;g++){                                                  \
        accA[g] = __builtin_amdgcn_mfma_f32_16x16x32_f16(ahA, bf[g][2*ks  ], accA[g], 0,0,0); \
        accB[g] = __builtin_amdgcn_mfma_f32_16x16x32_f16(ahB, bf[g][2*ks+1], accB[g], 0,0,0); \
      }                                                                       \
    }                                                                         \
    const float dnow  = dnS[(t)*4 + quad];                                    \
    const float dnext = ((t)+1 < T_) ? dnS[((t)+1)*4 + quad] : 0.f;           \
    float rg = sigmoidf_(c_r + accA[0][0] + accB[0][0]);                      \
    float zg = sigmoidf_(c_z + accA[1][0] + accB[1][0]);                      \
    float x  = c_n + rg*(accA[2][0] + accB[2][0] + bhnr);                     \
    float ng = 2.f/(1.f+__expf(-2.f*x)) - 1.f;                                \
    float hnew = (1.f - zg)*ng + zg*hc;                                       \
    pend_eu = f2bu(hnew*(1.f-dnow));                                          \
    float hv = (dnext > 0.5f) ? 0.f : hnew;                                   \
    hc = hv;                                                                  \
    hb[((t)+1)&1][(quad*4)*136 + col] = f2hu(hv);                             \
    asm volatile("s_waitcnt lgkmcnt(0)\n\ts_barrier" ::: "memory");           \
    c_r = hu2f(IR); c_z = hu2f(IZ); c_n = hu2f(IN);                           \
  }

  for (int t=0; t<T_; t+=4){
    GSTEP(t+0, aR,aZ,aN, dR,dZ,dN);
    GSTEP(t+1, bR,bZ,bN, aR,aZ,aN);
    GSTEP(t+2, cR,cZ,cN, bR,bZ,bN);
    GSTEP(t+3, dR,dZ,dN, cR,cZ,cN);
  }
#undef GSTEP

  ((ushort*)eb_out)[((size_t)(T_-1)*B_ + r0+quad)*D_ + col] = pend_eu;
  hout[(size_t)(r0+quad)*D_ + col] = hc;
}

// ---------------------------------------------------------------------------
// Weight-prep preamble.
// ---------------------------------------------------------------------------
__global__ __launch_bounds__(256)
void packall_k(const float* __restrict__ e1w, ushort* __restrict__ e1T,
               const float* __restrict__ e2w, ushort* __restrict__ e2T,
               const float* __restrict__ gWi, ushort* __restrict__ giT,
               const float* __restrict__ chw, __hip_bfloat16* __restrict__ bcatT,
               const float* __restrict__ uhw, __hip_bfloat16* __restrict__ uhwT,
               const float* __restrict__ uow, __hip_bfloat16* __restrict__ uowT,
               const float* __restrict__ v1w, __hip_bfloat16* __restrict__ v1wT,
               const float* __restrict__ v2w, __hip_bfloat16* __restrict__ v2wT)
{
  const int b = blockIdx.x, tid = threadIdx.x;
  if (b < 32){
    int idx = b*256 + tid;
    int n = idx >> 6, k = idx & 63;
    e1T[idx] = f2hu(e1w[k*128 + n]);
  } else if (b < 96){
    int idx = (b-32)*256 + tid;
    int n = idx >> 7, k = idx & 127;
    e2T[idx] = f2hu(e2w[k*128 + n]);
  } else if (b < 288){
    int idx = (b-96)*256 + tid;
    int n = idx >> 7, k = idx & 127;
    giT[idx] = f2hu(gWi[k*384 + n]);
  } else if (b < 416){
    int idx = (b-288)*256 + tid;
    int n = idx >> 7, k = idx & 127;
    float v = (n < 128) ? chw[k*128 + n] : chw[(128+k)*128 + (n-128)];
    bcatT[idx] = __float2bfloat16(v);
  } else if (b < 544){
    int idx = (b-416)*256 + tid;
    int r = idx >> 7, c = idx & 127;
    uhwT[c*256 + r] = __float2bfloat16(uhw[idx]);
  } else if (b < 608){
    int idx = (b-544)*256 + tid;
    int r = idx >> 7, c = idx & 127;
    uowT[c*128 + r] = __float2bfloat16(uow[idx]);
  } else if (b < 736){
    int idx = (b-608)*256 + tid;
    int r = idx >> 8, c = idx & 255;
    v1wT[c*128 + r] = __float2bfloat16(v1w[idx]);
  } else {
    int idx = (b-736)*256 + tid;
    int r = idx >> 8, c = idx & 255;
    v2wT[c*256 + r] = __float2bfloat16(v2w[idx]);
  }
}

extern "C" void kernel_launch(void* const* d_in, const int* in_sizes, int n_in,
                              void* d_out, int out_size, void* d_ws, size_t ws_size,
                              hipStream_t stream) {
  const float* hidden = (const float*)d_in[0];
  const float* obs    = (const float*)d_in[1];
  const int*   dones  = (const int*)  d_in[2];
  const float* e1w = (const float*)d_in[3];
  const float* e1b = (const float*)d_in[4];
  const float* e2w = (const float*)d_in[5];
  const float* e2b = (const float*)d_in[6];
  const float* gWi = (const float*)d_in[7];
  const float* gbi = (const float*)d_in[8];
  const float* gWh = (const float*)d_in[9];
  const float* gbhn= (const float*)d_in[10];
  const float* chw = (const float*)d_in[11];
  const float* chb = (const float*)d_in[12];
  const float* cow = (const float*)d_in[13];
  const float* cob = (const float*)d_in[14];
  const float* uhw = (const float*)d_in[15];
  const float* uhb = (const float*)d_in[16];
  const float* uow = (const float*)d_in[17];
  const float* uob = (const float*)d_in[18];
  const float* v1w = (const float*)d_in[19];
  const float* v1b = (const float*)d_in[20];
  const float* v2w = (const float*)d_in[21];
  const float* v2b = (const float*)d_in[22];
  const float* vow = (const float*)d_in[23];
  const float* vob = (const float*)d_in[24];
  (void)in_sizes; (void)n_in; (void)out_size;

  float* out_hidden = (float*)d_out;
  float* out_values = (float*)d_out + (size_t)B_*D_;

  // Arena (float-slot offsets).
  float* ws = (float*)d_ws;
  ushort* giH   = (ushort*)(ws + 10485760);           // [10.49M, 23.07M)
  __hip_bfloat16* Xe = (__hip_bfloat16*)(ws + 23068672); // [23.07M, 27.26M)
  ushort* wb    = (ushort*)(ws + 27262976);           // weights
  if (ws_size < (size_t)27500000 * sizeof(float)) return;

  __hip_bfloat16* bcatT = (__hip_bfloat16*)wb;           // [256][128]
  __hip_bfloat16* uhwT  = (__hip_bfloat16*)wb + 32768;   // [128][256]
  __hip_bfloat16* uowT  = (__hip_bfloat16*)wb + 65536;   // [128][128]
  __hip_bfloat16* v1wT  = (__hip_bfloat16*)wb + 81920;   // [256][128]
  __hip_bfloat16* v2wT  = (__hip_bfloat16*)wb + 114688;  // [256][256]
  ushort* e1wT = wb + 180224;   // [128][64]  fp16
  ushort* e2wT = wb + 188416;   // [128][128] fp16
  ushort* gWiT = wb + 204800;   // [384][128] fp16

  dim3 blk(256);
  packall_k<<<dim3(992), blk, 0, stream>>>(
    e1w, e1wT, e2w, e2wT, gWi, gWiT,
    chw, bcatT, uhw, uhwT, uow, uowT, v1w, v1wT, v2w, v2wT);

  // fused obs -> emb1 -> emb2 -> gi, 8 waves/block
  embgi_k<<<dim3(512), dim3(512), 0, stream>>>(obs, e1wT, e1b, e2wT, e2b, gWiT, gbi, giH);

  // MFMA GRU (best measured config)
  grum8_k<<<dim3(128), dim3(512), 0, stream>>>(giH, hidden, dones, gWh, gbhn, Xe, out_hidden);

  // whole post-GRU section (v6: all weight B-frags direct from L2)
  postgru_k<<<dim3(512), dim3(512), 0, stream>>>(Xe, bcatT, chb, cow, cob,
                                                 uhwT, uhb, uowT, uob, dones,
                                                 v1wT, v1b, v2wT, v2b, vow, vob, out_values);
}

// Round 18
// 296.781 us; speedup vs baseline: 1.2650x; 1.2650x over previous
//
#include <hip/hip_runtime.h>
#include <hip/hip_bf16.h>
#include <math.h>

#define T_ 128
#define NE_ 64
#define NA_ 8
#define B_ 512
#define OBS_ 64
#define D_ 128
#define CH_ 128
#define VH_ 256
#define M_ (T_*B_)   // 65536

typedef __attribute__((ext_vector_type(8))) short bf16x8;
typedef __attribute__((ext_vector_type(8))) _Float16 f16x8;
typedef __attribute__((ext_vector_type(4))) float f32x4;

__device__ __forceinline__ float sigmoidf_(float x){ return 1.f/(1.f+__expf(-x)); }
__device__ __forceinline__ unsigned short f2bu(float v){
  __hip_bfloat16 b = __float2bfloat16(v);
  return __builtin_bit_cast(unsigned short, b);
}
__device__ __forceinline__ float bu2f(unsigned short u){
  return __builtin_bit_cast(float, (unsigned int)u << 16);
}
__device__ __forceinline__ unsigned short f2hu(float v){
  _Float16 h = (_Float16)v;
  return __builtin_bit_cast(unsigned short, h);
}
__device__ __forceinline__ float hu2f(unsigned short u){
  return (float)__builtin_bit_cast(_Float16, u);
}

// ---------------------------------------------------------------------------
// embgi (R12 config, 8 waves).
// ---------------------------------------------------------------------------
__global__ __launch_bounds__(512)
void embgi_k(const float* __restrict__ obs,
             const ushort* __restrict__ e1wT, const float* __restrict__ e1b,
             const ushort* __restrict__ e2wT, const float* __restrict__ e2b,
             const ushort* __restrict__ gWiT, const float* __restrict__ gbi,
             ushort* __restrict__ giH)
{
  __shared__ ushort S1[128*136];
  __shared__ ushort S2[128*136];
  const int tid  = threadIdx.x;
  const int lane = tid & 63, wave = tid >> 6;   // 8 waves
  const int wm = wave >> 1, wn = wave & 1;      // 4x2 decomp, 32x64/wave
  const int quad = lane >> 4, ln = lane & 15;
  const int m0 = blockIdx.x * 128;

  f32x4 acc[2][4];

  // stage obs (f32 -> f16) into S1, e1wT into S2
  #pragma unroll
  for (int i=0;i<4;i++){
    int c4 = tid + i*512;                 // 2048 float4 groups
    int m = c4 >> 4, kf = (c4 & 15) * 4;
    float4 v = *(const float4*)&obs[(size_t)(m0+m)*OBS_ + kf];
    ushort4 h; h.x=f2hu(v.x); h.y=f2hu(v.y); h.z=f2hu(v.z); h.w=f2hu(v.w);
    *(ushort4*)&S1[m*136 + kf] = h;
  }
  #pragma unroll
  for (int i=0;i<2;i++){
    int c8 = tid + i*512;                 // 1024 ushort8
    int n = c8 >> 3, kq = (c8 & 7)*8;
    *(uint4*)&S2[n*136 + kq] = *(const uint4*)&e1wT[(size_t)n*64 + kq];
  }
  __syncthreads();

  // GEMM1: emb1 = relu(obs @ e1w + e1b), K=64
  #pragma unroll
  for (int i=0;i<2;i++)
    #pragma unroll
    for (int j=0;j<4;j++)
      #pragma unroll
      for (int r=0;r<4;r++) acc[i][j][r] = 0.f;
  #pragma unroll
  for (int ks=0; ks<2; ks++){
    const int kq = ks*32 + quad*8;
    f16x8 af[2], bfv[4];
    #pragma unroll
    for (int mt=0;mt<2;mt++)
      af[mt] = *(const f16x8*)&S1[(wm*32 + mt*16 + ln)*136 + kq];
    #pragma unroll
    for (int nt=0;nt<4;nt++)
      bfv[nt] = *(const f16x8*)&S2[(wn*64 + nt*16 + ln)*136 + kq];
    #pragma unroll
    for (int mt=0;mt<2;mt++)
      #pragma unroll
      for (int nt=0;nt<4;nt++)
        acc[mt][nt] = __builtin_amdgcn_mfma_f32_16x16x32_f16(af[mt], bfv[nt], acc[mt][nt], 0,0,0);
  }
  __syncthreads();   // everyone done reading S1/S2

  // emb1 -> S1; stage e2wT -> S2
  #pragma unroll
  for (int mt=0;mt<2;mt++)
    #pragma unroll
    for (int r=0;r<4;r++){
      int rl = wm*32 + mt*16 + quad*4 + r;
      #pragma unroll
      for (int nt=0;nt<4;nt++){
        int cl = wn*64 + nt*16 + ln;
        S1[rl*136 + cl] = f2hu(fmaxf(acc[mt][nt][r] + e1b[cl], 0.f));
      }
    }
  #pragma unroll
  for (int i=0;i<4;i++){
    int c8 = tid + i*512;
    int n = c8 >> 4, kq = (c8 & 15)*8;
    *(uint4*)&S2[n*136 + kq] = *(const uint4*)&e2wT[(size_t)n*128 + kq];
  }
  __syncthreads();

  // GEMM2: emb2 = relu(emb1 @ e2w + e2b), K=128
  #pragma unroll
  for (int i=0;i<2;i++)
    #pragma unroll
    for (int j=0;j<4;j++)
      #pragma unroll
      for (int r=0;r<4;r++) acc[i][j][r] = 0.f;
  #pragma unroll
  for (int ks=0; ks<4; ks++){
    const int kq = ks*32 + quad*8;
    f16x8 af[2], bfv[4];
    #pragma unroll
    for (int mt=0;mt<2;mt++)
      af[mt] = *(const f16x8*)&S1[(wm*32 + mt*16 + ln)*136 + kq];
    #pragma unroll
    for (int nt=0;nt<4;nt++)
      bfv[nt] = *(const f16x8*)&S2[(wn*64 + nt*16 + ln)*136 + kq];
    #pragma unroll
    for (int mt=0;mt<2;mt++)
      #pragma unroll
      for (int nt=0;nt<4;nt++)
        acc[mt][nt] = __builtin_amdgcn_mfma_f32_16x16x32_f16(af[mt], bfv[nt], acc[mt][nt], 0,0,0);
  }
  __syncthreads();   // done reading emb1(S1) / e2w(S2)

  // emb2 -> S1
  #pragma unroll
  for (int mt=0;mt<2;mt++)
    #pragma unroll
    for (int r=0;r<4;r++){
      int rl = wm*32 + mt*16 + quad*4 + r;
      #pragma unroll
      for (int nt=0;nt<4;nt++){
        int cl = wn*64 + nt*16 + ln;
        S1[rl*136 + cl] = f2hu(fmaxf(acc[mt][nt][r] + e2b[cl], 0.f));
      }
    }

  // gi chunks: gi[:, c*128 .. c*128+127] = emb2 @ gWi_chunk + gbi  (no act)
  for (int c=0; c<3; c++){
    #pragma unroll
    for (int i=0;i<4;i++){
      int c8 = tid + i*512;
      int n = c8 >> 4, kq = (c8 & 15)*8;
      *(uint4*)&S2[n*136 + kq] = *(const uint4*)&gWiT[(size_t)(c*128+n)*128 + kq];
    }
    __syncthreads();
    #pragma unroll
    for (int i=0;i<2;i++)
      #pragma unroll
      for (int j=0;j<4;j++)
        #pragma unroll
        for (int r=0;r<4;r++) acc[i][j][r] = 0.f;
    #pragma unroll
    for (int ks=0; ks<4; ks++){
      const int kq = ks*32 + quad*8;
      f16x8 af[2], bfv[4];
      #pragma unroll
      for (int mt=0;mt<2;mt++)
        af[mt] = *(const f16x8*)&S1[(wm*32 + mt*16 + ln)*136 + kq];
      #pragma unroll
      for (int nt=0;nt<4;nt++)
        bfv[nt] = *(const f16x8*)&S2[(wn*64 + nt*16 + ln)*136 + kq];
      #pragma unroll
      for (int mt=0;mt<2;mt++)
        #pragma unroll
        for (int nt=0;nt<4;nt++)
          acc[mt][nt] = __builtin_amdgcn_mfma_f32_16x16x32_f16(af[mt], bfv[nt], acc[mt][nt], 0,0,0);
    }
    __syncthreads();   // done reading S2 before next chunk restage
    #pragma unroll
    for (int mt=0;mt<2;mt++)
      #pragma unroll
      for (int r=0;r<4;r++){
        int row = m0 + wm*32 + mt*16 + quad*4 + r;
        #pragma unroll
        for (int nt=0;nt<4;nt++){
          int cl = wn*64 + nt*16 + ln;
          giH[(size_t)row*384 + c*128 + cl] = f2hu(acc[mt][nt][r] + gbi[c*128 + cl]);
        }
      }
  }
}

// ---------------------------------------------------------------------------
// postgru v5 (R16, measured 99.9us — BEST). Coupling B-frags direct from
// L2 (safe regime: 1 B-stream + acc[2]); dpre/update/v1/v2 keep LDS staging
// (R13/R17 proved acc[2][4] + 4 B-streams spills: FETCH/WRITE explode).
// 8 waves = measured optimum (4w=165 / 8w=113 / 16w=126 at R12 base).
// ---------------------------------------------------------------------------
__global__ __launch_bounds__(512, 1)
void postgru_k(const __hip_bfloat16* __restrict__ Xe, const __hip_bfloat16* __restrict__ bcatT,
               const float* __restrict__ chb, const float* __restrict__ cow,
               const float* __restrict__ cob,
               const __hip_bfloat16* __restrict__ uhwT, const float* __restrict__ uhb,
               const __hip_bfloat16* __restrict__ uowT, const float* __restrict__ uob,
               const int* __restrict__ dones,
               const __hip_bfloat16* __restrict__ v1wT, const float* __restrict__ v1b,
               const __hip_bfloat16* __restrict__ v2wT, const float* __restrict__ v2b,
               const float* __restrict__ vow, const float* __restrict__ vob,
               float* __restrict__ values)
{
  __shared__ ushort S1[128*136];                  // Xe tile (updated in place)
  __shared__ ushort Bs[128*136];                  // weight stage (non-coupling)
  __shared__ alignas(16) ushort Pool[2*128*136];  // A: XcS+AI+AJ / B: V1[2]
  __shared__ alignas(16) float cbw[CH_], cww[CH_];
  __shared__ float Cs[4][NA_][NA_];
  __shared__ float SRed[128];
  const int tid  = threadIdx.x;
  const int lane = tid & 63, wave = tid >> 6;     // 8 waves
  const int wm = wave >> 1, wn = wave & 1;        // 4x2 GEMM decomp
  const int quad = lane >> 4, ln = lane & 15;
  const int m0 = blockIdx.x * 128;

  const ushort* bcat = (const ushort*)bcatT;

  // phase-A carve of Pool (16B-aligned; AI/AJ row stride 132 f32 = 528B)
  ushort* XcS = Pool;                                              // 34816 B
  float (*AI)[132] = (float(*)[132])(Pool + 128*136);              // 16896 B
  float (*AJ)[132] = (float(*)[132])((char*)(Pool + 128*136) + 16896);

  // stage Xe -> S1, coupling vectors
  #pragma unroll
  for (int i=0;i<4;i++){
    int c8 = tid + i*512;
    int m = c8 >> 4, kq = (c8 & 15)*8;
    *(uint4*)&S1[m*136 + kq] = *(const uint4*)((const ushort*)Xe + (size_t)(m0+m)*128 + kq);
  }
  if (tid < 128){ cbw[tid] = chb[tid]; cww[tid] = cow[tid]; }
  const float cob0 = cob[0];
  __syncthreads();

  for (int it=0; it<2; it++){
    // ---- coupling: 4 groups of 4 envs (32 rows); bcat direct from L2 ----
    for (int g=0; g<4; g++){
      const int r0 = g*32;
      const int wrow = wave >> 2;      // 0..1  (16-row slabs of the group)
      const int wcol = wave & 3;       // 0..3  (32-col slabs)

      // ai: B-frags direct from bcatT rows 0..127
      {
        f32x4 accc[2];
        #pragma unroll
        for (int nt=0;nt<2;nt++)
          #pragma unroll
          for (int r=0;r<4;r++) accc[nt][r] = 0.f;
        #pragma unroll
        for (int ks=0; ks<4; ks++){
          const int kq = ks*32 + quad*8;
          bf16x8 af = *(const bf16x8*)&S1[(r0 + wrow*16 + ln)*136 + kq];
          #pragma unroll
          for (int nt=0;nt<2;nt++){
            int n = wcol*32 + nt*16 + ln;
            bf16x8 bfv = *(const bf16x8*)&bcat[(size_t)n*128 + kq];
            accc[nt] = __builtin_amdgcn_mfma_f32_16x16x32_bf16(af, bfv, accc[nt], 0,0,0);
          }
        }
        #pragma unroll
        for (int nt=0;nt<2;nt++)
          #pragma unroll
          for (int r=0;r<4;r++)
            AI[wrow*16 + quad*4 + r][wcol*32 + nt*16 + ln] = accc[nt][r];
      }
      // aj: B-frags direct from bcatT rows 128..255
      {
        f32x4 accc[2];
        #pragma unroll
        for (int nt=0;nt<2;nt++)
          #pragma unroll
          for (int r=0;r<4;r++) accc[nt][r] = 0.f;
        #pragma unroll
        for (int ks=0; ks<4; ks++){
          const int kq = ks*32 + quad*8;
          bf16x8 af = *(const bf16x8*)&S1[(r0 + wrow*16 + ln)*136 + kq];
          #pragma unroll
          for (int nt=0;nt<2;nt++){
            int n = wcol*32 + nt*16 + ln;
            bf16x8 bfv = *(const bf16x8*)&bcat[(size_t)(128+n)*128 + kq];
            accc[nt] = __builtin_amdgcn_mfma_f32_16x16x32_bf16(af, bfv, accc[nt], 0,0,0);
          }
        }
        #pragma unroll
        for (int nt=0;nt<2;nt++)
          #pragma unroll
          for (int r=0;r<4;r++)
            AJ[wrow*16 + quad*4 + r][wcol*32 + nt*16 + ln] = accc[nt][r];
      }
      __syncthreads();   // AI/AJ visible

      // Ch + C: thread = env(2)|i(3)|jg(1)|hq(3); 4 pairs (i, jg*4+jj)
      {
        const int env = tid >> 7;
        const int i   = (tid >> 4) & 7;
        const int jg  = (tid >> 3) & 1;
        const int hq  = tid & 7;
        const float* aiR = &AI[env*8 + i][0];
        const float* aj0 = &AJ[env*8 + jg*4 + 0][0];
        const float* aj1 = &AJ[env*8 + jg*4 + 1][0];
        const float* aj2 = &AJ[env*8 + jg*4 + 2][0];
        const float* aj3 = &AJ[env*8 + jg*4 + 3][0];
        float s0=0.f, s1=0.f, s2=0.f, s3=0.f;
        #pragma unroll
        for (int t=0; t<4; t++){
          int h = (hq + t*8)*4;
          float4 a4 = *(const float4*)&aiR[h];
          float4 c4 = *(const float4*)&cbw[h];
          float4 w4 = *(const float4*)&cww[h];
          float px = a4.x + c4.x, py = a4.y + c4.y, pz = a4.z + c4.z, pw = a4.w + c4.w;
          float4 b0 = *(const float4*)&aj0[h];
          s0 += fmaxf(px+b0.x,0.f)*w4.x + fmaxf(py+b0.y,0.f)*w4.y
              + fmaxf(pz+b0.z,0.f)*w4.z + fmaxf(pw+b0.w,0.f)*w4.w;
          float4 b1 = *(const float4*)&aj1[h];
          s1 += fmaxf(px+b1.x,0.f)*w4.x + fmaxf(py+b1.y,0.f)*w4.y
              + fmaxf(pz+b1.z,0.f)*w4.z + fmaxf(pw+b1.w,0.f)*w4.w;
          float4 b2 = *(const float4*)&aj2[h];
          s2 += fmaxf(px+b2.x,0.f)*w4.x + fmaxf(py+b2.y,0.f)*w4.y
              + fmaxf(pz+b2.z,0.f)*w4.z + fmaxf(pw+b2.w,0.f)*w4.w;
          float4 b3 = *(const float4*)&aj3[h];
          s3 += fmaxf(px+b3.x,0.f)*w4.x + fmaxf(py+b3.y,0.f)*w4.y
              + fmaxf(pz+b3.z,0.f)*w4.z + fmaxf(pw+b3.w,0.f)*w4.w;
        }
        s0 += __shfl_xor(s0,1); s0 += __shfl_xor(s0,2); s0 += __shfl_xor(s0,4);
        s1 += __shfl_xor(s1,1); s1 += __shfl_xor(s1,2); s1 += __shfl_xor(s1,4);
        s2 += __shfl_xor(s2,1); s2 += __shfl_xor(s2,2); s2 += __shfl_xor(s2,4);
        s3 += __shfl_xor(s3,1); s3 += __shfl_xor(s3,2); s3 += __shfl_xor(s3,4);
        if (hq == 0){
          int j0 = jg*4;
          float c0 = sigmoidf_(s0 + cob0); Cs[env][i][j0+0] = (i==j0+0)?0.f:c0;
          float c1 = sigmoidf_(s1 + cob0); Cs[env][i][j0+1] = (i==j0+1)?0.f:c1;
          float c2 = sigmoidf_(s2 + cob0); Cs[env][i][j0+2] = (i==j0+2)?0.f:c2;
          float c3 = sigmoidf_(s3 + cob0); Cs[env][i][j0+3] = (i==j0+3)?0.f:c3;
        }
      }
      __syncthreads();   // Cs visible

      // ctx = C @ e  -> XcS rows r0..r0+31 (bf16)
      {
        const int lr = tid >> 4;             // 0..31
        const int env = lr >> 3, ii = lr & 7;
        const int c0 = (tid & 15) * 8;
        #pragma unroll
        for (int cc=0; cc<2; cc++){
          int d = c0 + cc*4;
          float a0=0.f, a1=0.f, a2=0.f, a3=0.f;
          #pragma unroll
          for (int j=0;j<NA_;j++){
            float c = Cs[env][ii][j];
            ushort4 e4 = *(const ushort4*)&S1[(r0 + env*8 + j)*136 + d];
            a0 = fmaf(c, bu2f(e4.x), a0);
            a1 = fmaf(c, bu2f(e4.y), a1);
            a2 = fmaf(c, bu2f(e4.z), a2);
            a3 = fmaf(c, bu2f(e4.w), a3);
          }
          ushort4 o; o.x=f2bu(a0); o.y=f2bu(a1); o.z=f2bu(a2); o.w=f2bu(a3);
          *(ushort4*)&XcS[(r0 + lr)*136 + d] = o;
        }
      }
      __syncthreads();   // XcS group rows done; AI/AJ reusable next group
    }

    // ---- dpre = relu([Xe|ctx] @ uhwT + uhb), K=256 (staged Bs) ----
    f32x4 acc[2][4];
    #pragma unroll
    for (int i=0;i<2;i++)
      #pragma unroll
      for (int j=0;j<4;j++)
        #pragma unroll
        for (int r=0;r<4;r++) acc[i][j][r] = 0.f;

    #pragma unroll
    for (int kc=0; kc<2; kc++){
      #pragma unroll
      for (int i=0;i<4;i++){
        int c8 = tid + i*512;
        int n = c8 >> 4, kq = (c8 & 15)*8;
        *(uint4*)&Bs[n*136 + kq] = *(const uint4*)((const ushort*)uhwT + (size_t)n*256 + kc*128 + kq);
      }
      __syncthreads();
      const ushort* Ab = kc ? XcS : S1;
      #pragma unroll
      for (int ks=0; ks<4; ks++){
        const int kq = ks*32 + quad*8;
        bf16x8 af[2], bfv[4];
        #pragma unroll
        for (int mt=0;mt<2;mt++)
          af[mt] = *(const bf16x8*)&Ab[(wm*32 + mt*16 + ln)*136 + kq];
        #pragma unroll
        for (int nt=0;nt<4;nt++)
          bfv[nt] = *(const bf16x8*)&Bs[(wn*64 + nt*16 + ln)*136 + kq];
        #pragma unroll
        for (int mt=0;mt<2;mt++)
          #pragma unroll
          for (int nt=0;nt<4;nt++)
            acc[mt][nt] = __builtin_amdgcn_mfma_f32_16x16x32_bf16(af[mt], bfv[nt], acc[mt][nt], 0,0,0);
      }
      __syncthreads();
    }

    // dpre epilogue -> XcS (ctx consumed); stage uowT -> Bs
    #pragma unroll
    for (int i=0;i<4;i++){
      int c8 = tid + i*512;
      int n = c8 >> 4, kq = (c8 & 15)*8;
      *(uint4*)&Bs[n*136 + kq] = *(const uint4*)((const ushort*)uowT + (size_t)n*128 + kq);
    }
    #pragma unroll
    for (int mt=0;mt<2;mt++)
      #pragma unroll
      for (int r=0;r<4;r++){
        int rl = wm*32 + mt*16 + quad*4 + r;
        #pragma unroll
        for (int nt=0;nt<4;nt++){
          int cl = wn*64 + nt*16 + ln;
          XcS[rl*136 + cl] = f2bu(fmaxf(acc[mt][nt][r] + uhb[cl], 0.f));
        }
      }
    __syncthreads();

    // ---- update: Xe = (Xe + relu(dpre @ uowT + uob)) * alive, in LDS ----
    f32x4 acc2[2][4];
    #pragma unroll
    for (int i=0;i<2;i++)
      #pragma unroll
      for (int j=0;j<4;j++)
        #pragma unroll
        for (int r=0;r<4;r++) acc2[i][j][r] = 0.f;
    #pragma unroll
    for (int ks=0; ks<4; ks++){
      const int kq = ks*32 + quad*8;
      bf16x8 af[2], bfv[4];
      #pragma unroll
      for (int mt=0;mt<2;mt++)
        af[mt] = *(const bf16x8*)&XcS[(wm*32 + mt*16 + ln)*136 + kq];
      #pragma unroll
      for (int nt=0;nt<4;nt++)
        bfv[nt] = *(const bf16x8*)&Bs[(wn*64 + nt*16 + ln)*136 + kq];
      #pragma unroll
      for (int mt=0;mt<2;mt++)
        #pragma unroll
        for (int nt=0;nt<4;nt++)
          acc2[mt][nt] = __builtin_amdgcn_mfma_f32_16x16x32_bf16(af[mt], bfv[nt], acc2[mt][nt], 0,0,0);
    }
    #pragma unroll
    for (int mt=0;mt<2;mt++){
      #pragma unroll
      for (int r=0;r<4;r++){
        int rl = wm*32 + mt*16 + quad*4 + r;
        int row = m0 + rl;
        float al = (dones[row]!=0) ? 0.f : 1.f;
        #pragma unroll
        for (int nt=0;nt<4;nt++){
          int cl = wn*64 + nt*16 + ln;
          float v = fmaxf(acc2[mt][nt][r] + uob[cl], 0.f);
          v += bu2f(S1[rl*136 + cl]);
          v *= al;
          S1[rl*136 + cl] = f2bu(v);   // per-cell single owner
        }
      }
    }
    __syncthreads();   // new Xe visible for next iter / value head
  }

  // ================= value head (V1 overlays Pool) =================
  ushort* V1 = Pool;   // [2][128*136]; XcS/AI/AJ dead

  // phase 1: v1 halves
  for (int h=0; h<2; h++){
    #pragma unroll
    for (int i=0;i<4;i++){
      int c8 = tid + i*512;
      int n = c8 >> 4, kq = (c8 & 15)*8;
      *(uint4*)&Bs[n*136 + kq] = *(const uint4*)((const ushort*)v1wT + (size_t)(h*128+n)*128 + kq);
    }
    __syncthreads();
    f32x4 acc[2][4];
    #pragma unroll
    for (int i=0;i<2;i++)
      #pragma unroll
      for (int j=0;j<4;j++)
        #pragma unroll
        for (int r=0;r<4;r++) acc[i][j][r] = 0.f;
    #pragma unroll
    for (int ks=0; ks<4; ks++){
      const int kq = ks*32 + quad*8;
      bf16x8 af[2], bfv[4];
      #pragma unroll
      for (int mt=0;mt<2;mt++)
        af[mt] = *(const bf16x8*)&S1[(wm*32 + mt*16 + ln)*136 + kq];
      #pragma unroll
      for (int nt=0;nt<4;nt++)
        bfv[nt] = *(const bf16x8*)&Bs[(wn*64 + nt*16 + ln)*136 + kq];
      #pragma unroll
      for (int mt=0;mt<2;mt++)
        #pragma unroll
        for (int nt=0;nt<4;nt++)
          acc[mt][nt] = __builtin_amdgcn_mfma_f32_16x16x32_bf16(af[mt], bfv[nt], acc[mt][nt], 0,0,0);
    }
    __syncthreads();   // Bs free; orders V1 writes vs next stage
    #pragma unroll
    for (int mt=0;mt<2;mt++)
      #pragma unroll
      for (int r=0;r<4;r++){
        int rl = wm*32 + mt*16 + quad*4 + r;
        #pragma unroll
        for (int nt=0;nt<4;nt++){
          int cl = wn*64 + nt*16 + ln;
          V1[h*128*136 + rl*136 + cl] = f2bu(fmaxf(acc[mt][nt][r] + v1b[h*128 + cl], 0.f));
        }
      }
  }

  // phase 2: v2 (K=256 from V1) in 2 output chunks x 2 k-halves; dot with vow
  float s[2][4];
  #pragma unroll
  for (int mt=0;mt<2;mt++)
    #pragma unroll
    for (int r=0;r<4;r++) s[mt][r] = 0.f;

  for (int oc=0; oc<2; oc++){
    f32x4 acc[2][4];
    #pragma unroll
    for (int i=0;i<2;i++)
      #pragma unroll
      for (int j=0;j<4;j++)
        #pragma unroll
        for (int r=0;r<4;r++) acc[i][j][r] = 0.f;
    for (int kh=0; kh<2; kh++){
      #pragma unroll
      for (int i=0;i<4;i++){
        int c8 = tid + i*512;
        int n = c8 >> 4, kq = (c8 & 15)*8;
        *(uint4*)&Bs[n*136 + kq] = *(const uint4*)((const ushort*)v2wT + (size_t)(oc*128+n)*256 + kh*128 + kq);
      }
      __syncthreads();   // orders V1 writes (first iter) + stage before MFMA
      #pragma unroll
      for (int ks=0; ks<4; ks++){
        const int kq = ks*32 + quad*8;
        bf16x8 af[2], bfv[4];
        #pragma unroll
        for (int mt=0;mt<2;mt++)
          af[mt] = *(const bf16x8*)&V1[kh*128*136 + (wm*32 + mt*16 + ln)*136 + kq];
        #pragma unroll
        for (int nt=0;nt<4;nt++)
          bfv[nt] = *(const bf16x8*)&Bs[(wn*64 + nt*16 + ln)*136 + kq];
        #pragma unroll
        for (int mt=0;mt<2;mt++)
          #pragma unroll
          for (int nt=0;nt<4;nt++)
            acc[mt][nt] = __builtin_amdgcn_mfma_f32_16x16x32_bf16(af[mt], bfv[nt], acc[mt][nt], 0,0,0);
      }
      __syncthreads();   // Bs reusable
    }
    float v2bv[4], voww[4];
    #pragma unroll
    for (int nt=0;nt<4;nt++){
      int col = oc*128 + wn*64 + nt*16 + ln;
      v2bv[nt] = v2b[col];
      voww[nt] = vow[col];
    }
    #pragma unroll
    for (int mt=0;mt<2;mt++)
      #pragma unroll
      for (int r=0;r<4;r++){
        float p = 0.f;
        #pragma unroll
        for (int nt=0;nt<4;nt++)
          p += fmaxf(acc[mt][nt][r] + v2bv[nt], 0.f) * voww[nt];
        s[mt][r] += p;
      }
  }

  #pragma unroll
  for (int off=1; off<16; off<<=1)
    #pragma unroll
    for (int mt=0;mt<2;mt++)
      #pragma unroll
      for (int r=0;r<4;r++)
        s[mt][r] += __shfl_xor(s[mt][r], off);
  // cross-wave (wn 0/1) reduce via LDS, direct store (no atomics/memset)
  if (ln == 0 && wn == 1){
    #pragma unroll
    for (int mt=0;mt<2;mt++)
      #pragma unroll
      for (int r=0;r<4;r++)
        SRed[wm*32 + mt*16 + quad*4 + r] = s[mt][r];
  }
  __syncthreads();
  if (ln == 0 && wn == 0){
    float vob0 = vob[0];
    #pragma unroll
    for (int mt=0;mt<2;mt++)
      #pragma unroll
      for (int r=0;r<4;r++){
        int rl = wm*32 + mt*16 + quad*4 + r;
        values[m0 + rl] = s[mt][r] + SRed[rl] + vob0;
      }
  }
}

// ---------------------------------------------------------------------------
// MFMA GRU v10 (best measured: 84.9us, round 3). Parked.
// ---------------------------------------------------------------------------
__global__ __launch_bounds__(512, 1)
void grum8_k(const ushort* __restrict__ gih, const float* __restrict__ hidden0,
             const int* __restrict__ dones, const float* __restrict__ gWh,
             const float* __restrict__ bhn, __hip_bfloat16* __restrict__ eb_out,
             float* __restrict__ hout)
{
  __shared__ ushort wstg[32*392];
  __shared__ ushort hb[2][16*136];
  __shared__ float  dnS[T_*4];
  const int tid  = threadIdx.x;
  const int lane = tid & 63, wave = tid >> 6;
  const int quad = lane >> 4, ln = lane & 15;
  const int r0   = blockIdx.x * 4;
  const int col  = wave*16 + ln;
  const int lnb  = ln & 12;

  dnS[tid] = (dones[(size_t)(tid>>2)*B_ + r0 + (tid&3)] != 0) ? 1.f : 0.f;
  const float bhnr = bhn[col];

  for (int i=tid; i<16*136; i+=512){ hb[0][i]=0; hb[1][i]=0; }

  f16x8 bf[3][4];
  #pragma unroll
  for (int kc=0; kc<4; kc++){
    for (int i=tid; i<32*384; i+=512){
      int kk = i/384, c = i - kk*384;
      wstg[kk*392 + c] = f2hu(gWh[(size_t)(kc*32+kk)*384 + c]);
    }
    __syncthreads();
    #pragma unroll
    for (int g=0; g<3; g++){
      int c = g*128 + col;
      ushort tmp[8];
      #pragma unroll
      for (int j=0;j<8;j++) tmp[j] = wstg[(quad*8+j)*392 + c];
      bf[g][kc] = *(const f16x8*)tmp;
    }
    __syncthreads();
  }

  float hc = hidden0[(size_t)(r0+quad)*D_ + col];
  if (dnS[quad] > 0.5f) hc = 0.f;
  hb[0][(quad*4)*136 + col] = f2hu(hc);
  __syncthreads();

  const ushort* gbase = gih + ((size_t)(r0+quad))*384;
  const size_t  gstep = (size_t)B_*384;

  float c_r, c_z, c_n;
  c_r = hu2f(gbase[col]); c_z = hu2f(gbase[col+128]); c_n = hu2f(gbase[col+256]);
  ushort aR,aZ,aN, bR,bZ,bN, cR,cZ,cN, dR,dZ,dN;
  { const ushort* gp = gbase + 1*gstep; aR = gp[col]; aZ = gp[col+128]; aN = gp[col+256]; }
  { const ushort* gp = gbase + 2*gstep; bR = gp[col]; bZ = gp[col+128]; bN = gp[col+256]; }
  { const ushort* gp = gbase + 3*gstep; cR = gp[col]; cZ = gp[col+128]; cN = gp[col+256]; }
  dR=0; dZ=0; dN=0;

  ushort pend_eu = 0;

#define GSTEP(t, IR,IZ,IN, OR,OZ,ON)                                          \
  {                                                                           \
    if ((t) > 0)                                                              \
      ((ushort*)eb_out)[((size_t)((t)-1)*B_ + r0+quad)*D_ + col] = pend_eu;   \
    { int tl = (t)+4; if (tl > T_-1) tl = T_-1;                               \
      const ushort* gp = gbase + (size_t)tl*gstep;                            \
      OR = gp[col]; OZ = gp[col+128]; ON = gp[col+256]; }                     \
    const ushort* hbuf = hb[(t)&1];                                           \
    f32x4 accA[3], accB[3];                                                   \
    _Pragma("unroll")                                                         \
    for (int g=0;g<3;g++){                                                    \
      _Pragma("unroll")                                                       \
      for (int r=0;r<4;r++){ accA[g][r]=0.f; accB[g][r]=0.f; }                \
    }                                                                         \
    _Pragma("unroll")                                                         \
    for (int ks=0; ks<2; ks++){                                               \
      f16x8 ahA = *(const f16x8*)&hbuf[lnb*136 + (2*ks  )*32 + quad*8];       \
      f16x8 ahB = *(const f16x8*)&hbuf[lnb*136 + (2*ks+1)*32 + quad*8];       \
      _Pragma("unroll")                                                       \
      for (int g=0;g<3;g++){                                                  \
        accA[g] = __builtin_amdgcn_mfma_f32_16x16x32_f16(ahA, bf[g][2*ks  ], accA[g], 0,0,0); \
        accB[g] = __builtin_amdgcn_mfma_f32_16x16x32_f16(ahB, bf[g][2*ks+1], accB[g], 0,0,0); \
      }                                                                       \
    }                                                                         \
    const float dnow  = dnS[(t)*4 + quad];                                    \
    const float dnext = ((t)+1 < T_) ? dnS[((t)+1)*4 + quad] : 0.f;           \
    float rg = sigmoidf_(c_r + accA[0][0] + accB[0][0]);                      \
    float zg = sigmoidf_(c_z + accA[1][0] + accB[1][0]);                      \
    float x  = c_n + rg*(accA[2][0] + accB[2][0] + bhnr);                     \
    float ng = 2.f/(1.f+__expf(-2.f*x)) - 1.f;                                \
    float hnew = (1.f - zg)*ng + zg*hc;                                       \
    pend_eu = f2bu(hnew*(1.f-dnow));                                          \
    float hv = (dnext > 0.5f) ? 0.f : hnew;                                   \
    hc = hv;                                                                  \
    hb[((t)+1)&1][(quad*4)*136 + col] = f2hu(hv);                             \
    asm volatile("s_waitcnt lgkmcnt(0)\n\ts_barrier" ::: "memory");           \
    c_r = hu2f(IR); c_z = hu2f(IZ); c_n = hu2f(IN);                           \
  }

  for (int t=0; t<T_; t+=4){
    GSTEP(t+0, aR,aZ,aN, dR,dZ,dN);
    GSTEP(t+1, bR,bZ,bN, aR,aZ,aN);
    GSTEP(t+2, cR,cZ,cN, bR,bZ,bN);
    GSTEP(t+3, dR,dZ,dN, cR,cZ,cN);
  }
#undef GSTEP

  ((ushort*)eb_out)[((size_t)(T_-1)*B_ + r0+quad)*D_ + col] = pend_eu;
  hout[(size_t)(r0+quad)*D_ + col] = hc;
}

// ---------------------------------------------------------------------------
// Weight-prep preamble.
// ---------------------------------------------------------------------------
__global__ __launch_bounds__(256)
void packall_k(const float* __restrict__ e1w, ushort* __restrict__ e1T,
               const float* __restrict__ e2w, ushort* __restrict__ e2T,
               const float* __restrict__ gWi, ushort* __restrict__ giT,
               const float* __restrict__ chw, __hip_bfloat16* __restrict__ bcatT,
               const float* __restrict__ uhw, __hip_bfloat16* __restrict__ uhwT,
               const float* __restrict__ uow, __hip_bfloat16* __restrict__ uowT,
               const float* __restrict__ v1w, __hip_bfloat16* __restrict__ v1wT,
               const float* __restrict__ v2w, __hip_bfloat16* __restrict__ v2wT)
{
  const int b = blockIdx.x, tid = threadIdx.x;
  if (b < 32){
    int idx = b*256 + tid;
    int n = idx >> 6, k = idx & 63;
    e1T[idx] = f2hu(e1w[k*128 + n]);
  } else if (b < 96){
    int idx = (b-32)*256 + tid;
    int n = idx >> 7, k = idx & 127;
    e2T[idx] = f2hu(e2w[k*128 + n]);
  } else if (b < 288){
    int idx = (b-96)*256 + tid;
    int n = idx >> 7, k = idx & 127;
    giT[idx] = f2hu(gWi[k*384 + n]);
  } else if (b < 416){
    int idx = (b-288)*256 + tid;
    int n = idx >> 7, k = idx & 127;
    float v = (n < 128) ? chw[k*128 + n] : chw[(128+k)*128 + (n-128)];
    bcatT[idx] = __float2bfloat16(v);
  } else if (b < 544){
    int idx = (b-416)*256 + tid;
    int r = idx >> 7, c = idx & 127;
    uhwT[c*256 + r] = __float2bfloat16(uhw[idx]);
  } else if (b < 608){
    int idx = (b-544)*256 + tid;
    int r = idx >> 7, c = idx & 127;
    uowT[c*128 + r] = __float2bfloat16(uow[idx]);
  } else if (b < 736){
    int idx = (b-608)*256 + tid;
    int r = idx >> 8, c = idx & 255;
    v1wT[c*128 + r] = __float2bfloat16(v1w[idx]);
  } else {
    int idx = (b-736)*256 + tid;
    int r = idx >> 8, c = idx & 255;
    v2wT[c*256 + r] = __float2bfloat16(v2w[idx]);
  }
}

extern "C" void kernel_launch(void* const* d_in, const int* in_sizes, int n_in,
                              void* d_out, int out_size, void* d_ws, size_t ws_size,
                              hipStream_t stream) {
  const float* hidden = (const float*)d_in[0];
  const float* obs    = (const float*)d_in[1];
  const int*   dones  = (const int*)  d_in[2];
  const float* e1w = (const float*)d_in[3];
  const float* e1b = (const float*)d_in[4];
  const float* e2w = (const float*)d_in[5];
  const float* e2b = (const float*)d_in[6];
  const float* gWi = (const float*)d_in[7];
  const float* gbi = (const float*)d_in[8];
  const float* gWh = (const float*)d_in[9];
  const float* gbhn= (const float*)d_in[10];
  const float* chw = (const float*)d_in[11];
  const float* chb = (const float*)d_in[12];
  const float* cow = (const float*)d_in[13];
  const float* cob = (const float*)d_in[14];
  const float* uhw = (const float*)d_in[15];
  const float* uhb = (const float*)d_in[16];
  const float* uow = (const float*)d_in[17];
  const float* uob = (const float*)d_in[18];
  const float* v1w = (const float*)d_in[19];
  const float* v1b = (const float*)d_in[20];
  const float* v2w = (const float*)d_in[21];
  const float* v2b = (const float*)d_in[22];
  const float* vow = (const float*)d_in[23];
  const float* vob = (const float*)d_in[24];
  (void)in_sizes; (void)n_in; (void)out_size;

  float* out_hidden = (float*)d_out;
  float* out_values = (float*)d_out + (size_t)B_*D_;

  // Arena (float-slot offsets).
  float* ws = (float*)d_ws;
  ushort* giH   = (ushort*)(ws + 10485760);           // [10.49M, 23.07M)
  __hip_bfloat16* Xe = (__hip_bfloat16*)(ws + 23068672); // [23.07M, 27.26M)
  ushort* wb    = (ushort*)(ws + 27262976);           // weights
  if (ws_size < (size_t)27500000 * sizeof(float)) return;

  __hip_bfloat16* bcatT = (__hip_bfloat16*)wb;           // [256][128]
  __hip_bfloat16* uhwT  = (__hip_bfloat16*)wb + 32768;   // [128][256]
  __hip_bfloat16* uowT  = (__hip_bfloat16*)wb + 65536;   // [128][128]
  __hip_bfloat16* v1wT  = (__hip_bfloat16*)wb + 81920;   // [256][128]
  __hip_bfloat16* v2wT  = (__hip_bfloat16*)wb + 114688;  // [256][256]
  ushort* e1wT = wb + 180224;   // [128][64]  fp16
  ushort* e2wT = wb + 188416;   // [128][128] fp16
  ushort* gWiT = wb + 204800;   // [384][128] fp16

  dim3 blk(256);
  packall_k<<<dim3(992), blk, 0, stream>>>(
    e1w, e1wT, e2w, e2wT, gWi, gWiT,
    chw, bcatT, uhw, uhwT, uow, uowT, v1w, v1wT, v2w, v2wT);

  // fused obs -> emb1 -> emb2 -> gi, 8 waves/block
  embgi_k<<<dim3(512), dim3(512), 0, stream>>>(obs, e1wT, e1b, e2wT, e2b, gWiT, gbi, giH);

  // MFMA GRU (best measured config)
  grum8_k<<<dim3(128), dim3(512), 0, stream>>>(giH, hidden, dones, gWh, gbhn, Xe, out_hidden);

  // whole post-GRU section (R16 config: coupling direct-L2, rest staged)
  postgru_k<<<dim3(512), dim3(512), 0, stream>>>(Xe, bcatT, chb, cow, cob,
                                                 uhwT, uhb, uowT, uob, dones,
                                                 v1wT, v1b, v2wT, v2b, vow, vob, out_values);
}

// Round 20
// 296.197 us; speedup vs baseline: 1.2675x; 1.0020x over previous
//
#include <hip/hip_runtime.h>
#include <hip/hip_bf16.h>
#include <math.h>

#define T_ 128
#define NE_ 64
#define NA_ 8
#define B_ 512
#define OBS_ 64
#define D_ 128
#define CH_ 128
#define VH_ 256
#define M_ (T_*B_)   // 65536

typedef __attribute__((ext_vector_type(8))) short bf16x8;
typedef __attribute__((ext_vector_type(8))) _Float16 f16x8;
typedef __attribute__((ext_vector_type(4))) float f32x4;

__device__ __forceinline__ float sigmoidf_(float x){ return 1.f/(1.f+__expf(-x)); }
__device__ __forceinline__ unsigned short f2bu(float v){
  __hip_bfloat16 b = __float2bfloat16(v);
  return __builtin_bit_cast(unsigned short, b);
}
__device__ __forceinline__ float bu2f(unsigned short u){
  return __builtin_bit_cast(float, (unsigned int)u << 16);
}
__device__ __forceinline__ unsigned short f2hu(float v){
  _Float16 h = (_Float16)v;
  return __builtin_bit_cast(unsigned short, h);
}
__device__ __forceinline__ float hu2f(unsigned short u){
  return (float)__builtin_bit_cast(_Float16, u);
}

// ---------------------------------------------------------------------------
// embgi (R12 config, 8 waves).
// ---------------------------------------------------------------------------
__global__ __launch_bounds__(512)
void embgi_k(const float* __restrict__ obs,
             const ushort* __restrict__ e1wT, const float* __restrict__ e1b,
             const ushort* __restrict__ e2wT, const float* __restrict__ e2b,
             const ushort* __restrict__ gWiT, const float* __restrict__ gbi,
             ushort* __restrict__ giH)
{
  __shared__ ushort S1[128*136];
  __shared__ ushort S2[128*136];
  const int tid  = threadIdx.x;
  const int lane = tid & 63, wave = tid >> 6;   // 8 waves
  const int wm = wave >> 1, wn = wave & 1;      // 4x2 decomp, 32x64/wave
  const int quad = lane >> 4, ln = lane & 15;
  const int m0 = blockIdx.x * 128;

  f32x4 acc[2][4];

  // stage obs (f32 -> f16) into S1, e1wT into S2
  #pragma unroll
  for (int i=0;i<4;i++){
    int c4 = tid + i*512;                 // 2048 float4 groups
    int m = c4 >> 4, kf = (c4 & 15) * 4;
    float4 v = *(const float4*)&obs[(size_t)(m0+m)*OBS_ + kf];
    ushort4 h; h.x=f2hu(v.x); h.y=f2hu(v.y); h.z=f2hu(v.z); h.w=f2hu(v.w);
    *(ushort4*)&S1[m*136 + kf] = h;
  }
  #pragma unroll
  for (int i=0;i<2;i++){
    int c8 = tid + i*512;                 // 1024 ushort8
    int n = c8 >> 3, kq = (c8 & 7)*8;
    *(uint4*)&S2[n*136 + kq] = *(const uint4*)&e1wT[(size_t)n*64 + kq];
  }
  __syncthreads();

  // GEMM1: emb1 = relu(obs @ e1w + e1b), K=64
  #pragma unroll
  for (int i=0;i<2;i++)
    #pragma unroll
    for (int j=0;j<4;j++)
      #pragma unroll
      for (int r=0;r<4;r++) acc[i][j][r] = 0.f;
  #pragma unroll
  for (int ks=0; ks<2; ks++){
    const int kq = ks*32 + quad*8;
    f16x8 af[2], bfv[4];
    #pragma unroll
    for (int mt=0;mt<2;mt++)
      af[mt] = *(const f16x8*)&S1[(wm*32 + mt*16 + ln)*136 + kq];
    #pragma unroll
    for (int nt=0;nt<4;nt++)
      bfv[nt] = *(const f16x8*)&S2[(wn*64 + nt*16 + ln)*136 + kq];
    #pragma unroll
    for (int mt=0;mt<2;mt++)
      #pragma unroll
      for (int nt=0;nt<4;nt++)
        acc[mt][nt] = __builtin_amdgcn_mfma_f32_16x16x32_f16(af[mt], bfv[nt], acc[mt][nt], 0,0,0);
  }
  __syncthreads();   // everyone done reading S1/S2

  // emb1 -> S1; stage e2wT -> S2
  #pragma unroll
  for (int mt=0;mt<2;mt++)
    #pragma unroll
    for (int r=0;r<4;r++){
      int rl = wm*32 + mt*16 + quad*4 + r;
      #pragma unroll
      for (int nt=0;nt<4;nt++){
        int cl = wn*64 + nt*16 + ln;
        S1[rl*136 + cl] = f2hu(fmaxf(acc[mt][nt][r] + e1b[cl], 0.f));
      }
    }
  #pragma unroll
  for (int i=0;i<4;i++){
    int c8 = tid + i*512;
    int n = c8 >> 4, kq = (c8 & 15)*8;
    *(uint4*)&S2[n*136 + kq] = *(const uint4*)&e2wT[(size_t)n*128 + kq];
  }
  __syncthreads();

  // GEMM2: emb2 = relu(emb1 @ e2w + e2b), K=128
  #pragma unroll
  for (int i=0;i<2;i++)
    #pragma unroll
    for (int j=0;j<4;j++)
      #pragma unroll
      for (int r=0;r<4;r++) acc[i][j][r] = 0.f;
  #pragma unroll
  for (int ks=0; ks<4; ks++){
    const int kq = ks*32 + quad*8;
    f16x8 af[2], bfv[4];
    #pragma unroll
    for (int mt=0;mt<2;mt++)
      af[mt] = *(const f16x8*)&S1[(wm*32 + mt*16 + ln)*136 + kq];
    #pragma unroll
    for (int nt=0;nt<4;nt++)
      bfv[nt] = *(const f16x8*)&S2[(wn*64 + nt*16 + ln)*136 + kq];
    #pragma unroll
    for (int mt=0;mt<2;mt++)
      #pragma unroll
      for (int nt=0;nt<4;nt++)
        acc[mt][nt] = __builtin_amdgcn_mfma_f32_16x16x32_f16(af[mt], bfv[nt], acc[mt][nt], 0,0,0);
  }
  __syncthreads();   // done reading emb1(S1) / e2w(S2)

  // emb2 -> S1
  #pragma unroll
  for (int mt=0;mt<2;mt++)
    #pragma unroll
    for (int r=0;r<4;r++){
      int rl = wm*32 + mt*16 + quad*4 + r;
      #pragma unroll
      for (int nt=0;nt<4;nt++){
        int cl = wn*64 + nt*16 + ln;
        S1[rl*136 + cl] = f2hu(fmaxf(acc[mt][nt][r] + e2b[cl], 0.f));
      }
    }

  // gi chunks: gi[:, c*128 .. c*128+127] = emb2 @ gWi_chunk + gbi  (no act)
  for (int c=0; c<3; c++){
    #pragma unroll
    for (int i=0;i<4;i++){
      int c8 = tid + i*512;
      int n = c8 >> 4, kq = (c8 & 15)*8;
      *(uint4*)&S2[n*136 + kq] = *(const uint4*)&gWiT[(size_t)(c*128+n)*128 + kq];
    }
    __syncthreads();
    #pragma unroll
    for (int i=0;i<2;i++)
      #pragma unroll
      for (int j=0;j<4;j++)
        #pragma unroll
        for (int r=0;r<4;r++) acc[i][j][r] = 0.f;
    #pragma unroll
    for (int ks=0; ks<4; ks++){
      const int kq = ks*32 + quad*8;
      f16x8 af[2], bfv[4];
      #pragma unroll
      for (int mt=0;mt<2;mt++)
        af[mt] = *(const f16x8*)&S1[(wm*32 + mt*16 + ln)*136 + kq];
      #pragma unroll
      for (int nt=0;nt<4;nt++)
        bfv[nt] = *(const f16x8*)&S2[(wn*64 + nt*16 + ln)*136 + kq];
      #pragma unroll
      for (int mt=0;mt<2;mt++)
        #pragma unroll
        for (int nt=0;nt<4;nt++)
          acc[mt][nt] = __builtin_amdgcn_mfma_f32_16x16x32_f16(af[mt], bfv[nt], acc[mt][nt], 0,0,0);
    }
    __syncthreads();   // done reading S2 before next chunk restage
    #pragma unroll
    for (int mt=0;mt<2;mt++)
      #pragma unroll
      for (int r=0;r<4;r++){
        int row = m0 + wm*32 + mt*16 + quad*4 + r;
        #pragma unroll
        for (int nt=0;nt<4;nt++){
          int cl = wn*64 + nt*16 + ln;
          giH[(size_t)row*384 + c*128 + cl] = f2hu(acc[mt][nt][r] + gbi[c*128 + cl]);
        }
      }
  }
}

// ---------------------------------------------------------------------------
// postgru v5 (R16, measured 99.9-102us — BEST). Coupling B-frags direct from
// L2 (safe regime: 1 B-stream + acc[2]); dpre/update/v1/v2 keep LDS staging
// (R13/R17 proved acc[2][4] + 4 B-streams spills: FETCH/WRITE explode).
// 8 waves = measured optimum (4w=165 / 8w=113 / 16w=126 at R12 base).
// ---------------------------------------------------------------------------
__global__ __launch_bounds__(512, 1)
void postgru_k(const __hip_bfloat16* __restrict__ Xe, const __hip_bfloat16* __restrict__ bcatT,
               const float* __restrict__ chb, const float* __restrict__ cow,
               const float* __restrict__ cob,
               const __hip_bfloat16* __restrict__ uhwT, const float* __restrict__ uhb,
               const __hip_bfloat16* __restrict__ uowT, const float* __restrict__ uob,
               const int* __restrict__ dones,
               const __hip_bfloat16* __restrict__ v1wT, const float* __restrict__ v1b,
               const __hip_bfloat16* __restrict__ v2wT, const float* __restrict__ v2b,
               const float* __restrict__ vow, const float* __restrict__ vob,
               float* __restrict__ values)
{
  __shared__ ushort S1[128*136];                  // Xe tile (updated in place)
  __shared__ ushort Bs[128*136];                  // weight stage (non-coupling)
  __shared__ alignas(16) ushort Pool[2*128*136];  // A: XcS+AI+AJ / B: V1[2]
  __shared__ alignas(16) float cbw[CH_], cww[CH_];
  __shared__ float Cs[4][NA_][NA_];
  __shared__ float SRed[128];
  const int tid  = threadIdx.x;
  const int lane = tid & 63, wave = tid >> 6;     // 8 waves
  const int wm = wave >> 1, wn = wave & 1;        // 4x2 GEMM decomp
  const int quad = lane >> 4, ln = lane & 15;
  const int m0 = blockIdx.x * 128;

  const ushort* bcat = (const ushort*)bcatT;

  // phase-A carve of Pool (16B-aligned; AI/AJ row stride 132 f32 = 528B)
  ushort* XcS = Pool;                                              // 34816 B
  float (*AI)[132] = (float(*)[132])(Pool + 128*136);              // 16896 B
  float (*AJ)[132] = (float(*)[132])((char*)(Pool + 128*136) + 16896);

  // stage Xe -> S1, coupling vectors
  #pragma unroll
  for (int i=0;i<4;i++){
    int c8 = tid + i*512;
    int m = c8 >> 4, kq = (c8 & 15)*8;
    *(uint4*)&S1[m*136 + kq] = *(const uint4*)((const ushort*)Xe + (size_t)(m0+m)*128 + kq);
  }
  if (tid < 128){ cbw[tid] = chb[tid]; cww[tid] = cow[tid]; }
  const float cob0 = cob[0];
  __syncthreads();

  for (int it=0; it<2; it++){
    // ---- coupling: 4 groups of 4 envs (32 rows); bcat direct from L2 ----
    for (int g=0; g<4; g++){
      const int r0 = g*32;
      const int wrow = wave >> 2;      // 0..1  (16-row slabs of the group)
      const int wcol = wave & 3;       // 0..3  (32-col slabs)

      // ai: B-frags direct from bcatT rows 0..127
      {
        f32x4 accc[2];
        #pragma unroll
        for (int nt=0;nt<2;nt++)
          #pragma unroll
          for (int r=0;r<4;r++) accc[nt][r] = 0.f;
        #pragma unroll
        for (int ks=0; ks<4; ks++){
          const int kq = ks*32 + quad*8;
          bf16x8 af = *(const bf16x8*)&S1[(r0 + wrow*16 + ln)*136 + kq];
          #pragma unroll
          for (int nt=0;nt<2;nt++){
            int n = wcol*32 + nt*16 + ln;
            bf16x8 bfv = *(const bf16x8*)&bcat[(size_t)n*128 + kq];
            accc[nt] = __builtin_amdgcn_mfma_f32_16x16x32_bf16(af, bfv, accc[nt], 0,0,0);
          }
        }
        #pragma unroll
        for (int nt=0;nt<2;nt++)
          #pragma unroll
          for (int r=0;r<4;r++)
            AI[wrow*16 + quad*4 + r][wcol*32 + nt*16 + ln] = accc[nt][r];
      }
      // aj: B-frags direct from bcatT rows 128..255
      {
        f32x4 accc[2];
        #pragma unroll
        for (int nt=0;nt<2;nt++)
          #pragma unroll
          for (int r=0;r<4;r++) accc[nt][r] = 0.f;
        #pragma unroll
        for (int ks=0; ks<4; ks++){
          const int kq = ks*32 + quad*8;
          bf16x8 af = *(const bf16x8*)&S1[(r0 + wrow*16 + ln)*136 + kq];
          #pragma unroll
          for (int nt=0;nt<2;nt++){
            int n = wcol*32 + nt*16 + ln;
            bf16x8 bfv = *(const bf16x8*)&bcat[(size_t)(128+n)*128 + kq];
            accc[nt] = __builtin_amdgcn_mfma_f32_16x16x32_bf16(af, bfv, accc[nt], 0,0,0);
          }
        }
        #pragma unroll
        for (int nt=0;nt<2;nt++)
          #pragma unroll
          for (int r=0;r<4;r++)
            AJ[wrow*16 + quad*4 + r][wcol*32 + nt*16 + ln] = accc[nt][r];
      }
      __syncthreads();   // AI/AJ visible

      // Ch + C: thread = env(2)|i(3)|jg(1)|hq(3); 4 pairs (i, jg*4+jj)
      {
        const int env = tid >> 7;
        const int i   = (tid >> 4) & 7;
        const int jg  = (tid >> 3) & 1;
        const int hq  = tid & 7;
        const float* aiR = &AI[env*8 + i][0];
        const float* aj0 = &AJ[env*8 + jg*4 + 0][0];
        const float* aj1 = &AJ[env*8 + jg*4 + 1][0];
        const float* aj2 = &AJ[env*8 + jg*4 + 2][0];
        const float* aj3 = &AJ[env*8 + jg*4 + 3][0];
        float s0=0.f, s1=0.f, s2=0.f, s3=0.f;
        #pragma unroll
        for (int t=0; t<4; t++){
          int h = (hq + t*8)*4;
          float4 a4 = *(const float4*)&aiR[h];
          float4 c4 = *(const float4*)&cbw[h];
          float4 w4 = *(const float4*)&cww[h];
          float px = a4.x + c4.x, py = a4.y + c4.y, pz = a4.z + c4.z, pw = a4.w + c4.w;
          float4 b0 = *(const float4*)&aj0[h];
          s0 += fmaxf(px+b0.x,0.f)*w4.x + fmaxf(py+b0.y,0.f)*w4.y
              + fmaxf(pz+b0.z,0.f)*w4.z + fmaxf(pw+b0.w,0.f)*w4.w;
          float4 b1 = *(const float4*)&aj1[h];
          s1 += fmaxf(px+b1.x,0.f)*w4.x + fmaxf(py+b1.y,0.f)*w4.y
              + fmaxf(pz+b1.z,0.f)*w4.z + fmaxf(pw+b1.w,0.f)*w4.w;
          float4 b2 = *(const float4*)&aj2[h];
          s2 += fmaxf(px+b2.x,0.f)*w4.x + fmaxf(py+b2.y,0.f)*w4.y
              + fmaxf(pz+b2.z,0.f)*w4.z + fmaxf(pw+b2.w,0.f)*w4.w;
          float4 b3 = *(const float4*)&aj3[h];
          s3 += fmaxf(px+b3.x,0.f)*w4.x + fmaxf(py+b3.y,0.f)*w4.y
              + fmaxf(pz+b3.z,0.f)*w4.z + fmaxf(pw+b3.w,0.f)*w4.w;
        }
        s0 += __shfl_xor(s0,1); s0 += __shfl_xor(s0,2); s0 += __shfl_xor(s0,4);
        s1 += __shfl_xor(s1,1); s1 += __shfl_xor(s1,2); s1 += __shfl_xor(s1,4);
        s2 += __shfl_xor(s2,1); s2 += __shfl_xor(s2,2); s2 += __shfl_xor(s2,4);
        s3 += __shfl_xor(s3,1); s3 += __shfl_xor(s3,2); s3 += __shfl_xor(s3,4);
        if (hq == 0){
          int j0 = jg*4;
          float c0 = sigmoidf_(s0 + cob0); Cs[env][i][j0+0] = (i==j0+0)?0.f:c0;
          float c1 = sigmoidf_(s1 + cob0); Cs[env][i][j0+1] = (i==j0+1)?0.f:c1;
          float c2 = sigmoidf_(s2 + cob0); Cs[env][i][j0+2] = (i==j0+2)?0.f:c2;
          float c3 = sigmoidf_(s3 + cob0); Cs[env][i][j0+3] = (i==j0+3)?0.f:c3;
        }
      }
      __syncthreads();   // Cs visible

      // ctx = C @ e  -> XcS rows r0..r0+31 (bf16)
      {
        const int lr = tid >> 4;             // 0..31
        const int env = lr >> 3, ii = lr & 7;
        const int c0 = (tid & 15) * 8;
        #pragma unroll
        for (int cc=0; cc<2; cc++){
          int d = c0 + cc*4;
          float a0=0.f, a1=0.f, a2=0.f, a3=0.f;
          #pragma unroll
          for (int j=0;j<NA_;j++){
            float c = Cs[env][ii][j];
            ushort4 e4 = *(const ushort4*)&S1[(r0 + env*8 + j)*136 + d];
            a0 = fmaf(c, bu2f(e4.x), a0);
            a1 = fmaf(c, bu2f(e4.y), a1);
            a2 = fmaf(c, bu2f(e4.z), a2);
            a3 = fmaf(c, bu2f(e4.w), a3);
          }
          ushort4 o; o.x=f2bu(a0); o.y=f2bu(a1); o.z=f2bu(a2); o.w=f2bu(a3);
          *(ushort4*)&XcS[(r0 + lr)*136 + d] = o;
        }
      }
      __syncthreads();   // XcS group rows done; AI/AJ reusable next group
    }

    // ---- dpre = relu([Xe|ctx] @ uhwT + uhb), K=256 (staged Bs) ----
    f32x4 acc[2][4];
    #pragma unroll
    for (int i=0;i<2;i++)
      #pragma unroll
      for (int j=0;j<4;j++)
        #pragma unroll
        for (int r=0;r<4;r++) acc[i][j][r] = 0.f;

    #pragma unroll
    for (int kc=0; kc<2; kc++){
      #pragma unroll
      for (int i=0;i<4;i++){
        int c8 = tid + i*512;
        int n = c8 >> 4, kq = (c8 & 15)*8;
        *(uint4*)&Bs[n*136 + kq] = *(const uint4*)((const ushort*)uhwT + (size_t)n*256 + kc*128 + kq);
      }
      __syncthreads();
      const ushort* Ab = kc ? XcS : S1;
      #pragma unroll
      for (int ks=0; ks<4; ks++){
        const int kq = ks*32 + quad*8;
        bf16x8 af[2], bfv[4];
        #pragma unroll
        for (int mt=0;mt<2;mt++)
          af[mt] = *(const bf16x8*)&Ab[(wm*32 + mt*16 + ln)*136 + kq];
        #pragma unroll
        for (int nt=0;nt<4;nt++)
          bfv[nt] = *(const bf16x8*)&Bs[(wn*64 + nt*16 + ln)*136 + kq];
        #pragma unroll
        for (int mt=0;mt<2;mt++)
          #pragma unroll
          for (int nt=0;nt<4;nt++)
            acc[mt][nt] = __builtin_amdgcn_mfma_f32_16x16x32_bf16(af[mt], bfv[nt], acc[mt][nt], 0,0,0);
      }
      __syncthreads();
    }

    // dpre epilogue -> XcS (ctx consumed); stage uowT -> Bs
    #pragma unroll
    for (int i=0;i<4;i++){
      int c8 = tid + i*512;
      int n = c8 >> 4, kq = (c8 & 15)*8;
      *(uint4*)&Bs[n*136 + kq] = *(const uint4*)((const ushort*)uowT + (size_t)n*128 + kq);
    }
    #pragma unroll
    for (int mt=0;mt<2;mt++)
      #pragma unroll
      for (int r=0;r<4;r++){
        int rl = wm*32 + mt*16 + quad*4 + r;
        #pragma unroll
        for (int nt=0;nt<4;nt++){
          int cl = wn*64 + nt*16 + ln;
          XcS[rl*136 + cl] = f2bu(fmaxf(acc[mt][nt][r] + uhb[cl], 0.f));
        }
      }
    __syncthreads();

    // ---- update: Xe = (Xe + relu(dpre @ uowT + uob)) * alive, in LDS ----
    f32x4 acc2[2][4];
    #pragma unroll
    for (int i=0;i<2;i++)
      #pragma unroll
      for (int j=0;j<4;j++)
        #pragma unroll
        for (int r=0;r<4;r++) acc2[i][j][r] = 0.f;
    #pragma unroll
    for (int ks=0; ks<4; ks++){
      const int kq = ks*32 + quad*8;
      bf16x8 af[2], bfv[4];
      #pragma unroll
      for (int mt=0;mt<2;mt++)
        af[mt] = *(const bf16x8*)&XcS[(wm*32 + mt*16 + ln)*136 + kq];
      #pragma unroll
      for (int nt=0;nt<4;nt++)
        bfv[nt] = *(const bf16x8*)&Bs[(wn*64 + nt*16 + ln)*136 + kq];
      #pragma unroll
      for (int mt=0;mt<2;mt++)
        #pragma unroll
        for (int nt=0;nt<4;nt++)
          acc2[mt][nt] = __builtin_amdgcn_mfma_f32_16x16x32_bf16(af[mt], bfv[nt], acc2[mt][nt], 0,0,0);
    }
    #pragma unroll
    for (int mt=0;mt<2;mt++){
      #pragma unroll
      for (int r=0;r<4;r++){
        int rl = wm*32 + mt*16 + quad*4 + r;
        int row = m0 + rl;
        float al = (dones[row]!=0) ? 0.f : 1.f;
        #pragma unroll
        for (int nt=0;nt<4;nt++){
          int cl = wn*64 + nt*16 + ln;
          float v = fmaxf(acc2[mt][nt][r] + uob[cl], 0.f);
          v += bu2f(S1[rl*136 + cl]);
          v *= al;
          S1[rl*136 + cl] = f2bu(v);   // per-cell single owner
        }
      }
    }
    __syncthreads();   // new Xe visible for next iter / value head
  }

  // ================= value head (V1 overlays Pool) =================
  ushort* V1 = Pool;   // [2][128*136]; XcS/AI/AJ dead

  // phase 1: v1 halves
  for (int h=0; h<2; h++){
    #pragma unroll
    for (int i=0;i<4;i++){
      int c8 = tid + i*512;
      int n = c8 >> 4, kq = (c8 & 15)*8;
      *(uint4*)&Bs[n*136 + kq] = *(const uint4*)((const ushort*)v1wT + (size_t)(h*128+n)*128 + kq);
    }
    __syncthreads();
    f32x4 acc[2][4];
    #pragma unroll
    for (int i=0;i<2;i++)
      #pragma unroll
      for (int j=0;j<4;j++)
        #pragma unroll
        for (int r=0;r<4;r++) acc[i][j][r] = 0.f;
    #pragma unroll
    for (int ks=0; ks<4; ks++){
      const int kq = ks*32 + quad*8;
      bf16x8 af[2], bfv[4];
      #pragma unroll
      for (int mt=0;mt<2;mt++)
        af[mt] = *(const bf16x8*)&S1[(wm*32 + mt*16 + ln)*136 + kq];
      #pragma unroll
      for (int nt=0;nt<4;nt++)
        bfv[nt] = *(const bf16x8*)&Bs[(wn*64 + nt*16 + ln)*136 + kq];
      #pragma unroll
      for (int mt=0;mt<2;mt++)
        #pragma unroll
        for (int nt=0;nt<4;nt++)
          acc[mt][nt] = __builtin_amdgcn_mfma_f32_16x16x32_bf16(af[mt], bfv[nt], acc[mt][nt], 0,0,0);
    }
    __syncthreads();   // Bs free; orders V1 writes vs next stage
    #pragma unroll
    for (int mt=0;mt<2;mt++)
      #pragma unroll
      for (int r=0;r<4;r++){
        int rl = wm*32 + mt*16 + quad*4 + r;
        #pragma unroll
        for (int nt=0;nt<4;nt++){
          int cl = wn*64 + nt*16 + ln;
          V1[h*128*136 + rl*136 + cl] = f2bu(fmaxf(acc[mt][nt][r] + v1b[h*128 + cl], 0.f));
        }
      }
  }

  // phase 2: v2 (K=256 from V1) in 2 output chunks x 2 k-halves; dot with vow
  float s[2][4];
  #pragma unroll
  for (int mt=0;mt<2;mt++)
    #pragma unroll
    for (int r=0;r<4;r++) s[mt][r] = 0.f;

  for (int oc=0; oc<2; oc++){
    f32x4 acc[2][4];
    #pragma unroll
    for (int i=0;i<2;i++)
      #pragma unroll
      for (int j=0;j<4;j++)
        #pragma unroll
        for (int r=0;r<4;r++) acc[i][j][r] = 0.f;
    for (int kh=0; kh<2; kh++){
      #pragma unroll
      for (int i=0;i<4;i++){
        int c8 = tid + i*512;
        int n = c8 >> 4, kq = (c8 & 15)*8;
        *(uint4*)&Bs[n*136 + kq] = *(const uint4*)((const ushort*)v2wT + (size_t)(oc*128+n)*256 + kh*128 + kq);
      }
      __syncthreads();   // orders V1 writes (first iter) + stage before MFMA
      #pragma unroll
      for (int ks=0; ks<4; ks++){
        const int kq = ks*32 + quad*8;
        bf16x8 af[2], bfv[4];
        #pragma unroll
        for (int mt=0;mt<2;mt++)
          af[mt] = *(const bf16x8*)&V1[kh*128*136 + (wm*32 + mt*16 + ln)*136 + kq];
        #pragma unroll
        for (int nt=0;nt<4;nt++)
          bfv[nt] = *(const bf16x8*)&Bs[(wn*64 + nt*16 + ln)*136 + kq];
        #pragma unroll
        for (int mt=0;mt<2;mt++)
          #pragma unroll
          for (int nt=0;nt<4;nt++)
            acc[mt][nt] = __builtin_amdgcn_mfma_f32_16x16x32_bf16(af[mt], bfv[nt], acc[mt][nt], 0,0,0);
      }
      __syncthreads();   // Bs reusable
    }
    float v2bv[4], voww[4];
    #pragma unroll
    for (int nt=0;nt<4;nt++){
      int col = oc*128 + wn*64 + nt*16 + ln;
      v2bv[nt] = v2b[col];
      voww[nt] = vow[col];
    }
    #pragma unroll
    for (int mt=0;mt<2;mt++)
      #pragma unroll
      for (int r=0;r<4;r++){
        float p = 0.f;
        #pragma unroll
        for (int nt=0;nt<4;nt++)
          p += fmaxf(acc[mt][nt][r] + v2bv[nt], 0.f) * voww[nt];
        s[mt][r] += p;
      }
  }

  #pragma unroll
  for (int off=1; off<16; off<<=1)
    #pragma unroll
    for (int mt=0;mt<2;mt++)
      #pragma unroll
      for (int r=0;r<4;r++)
        s[mt][r] += __shfl_xor(s[mt][r], off);
  // cross-wave (wn 0/1) reduce via LDS, direct store (no atomics/memset)
  if (ln == 0 && wn == 1){
    #pragma unroll
    for (int mt=0;mt<2;mt++)
      #pragma unroll
      for (int r=0;r<4;r++)
        SRed[wm*32 + mt*16 + quad*4 + r] = s[mt][r];
  }
  __syncthreads();
  if (ln == 0 && wn == 0){
    float vob0 = vob[0];
    #pragma unroll
    for (int mt=0;mt<2;mt++)
      #pragma unroll
      for (int r=0;r<4;r++){
        int rl = wm*32 + mt*16 + quad*4 + r;
        values[m0 + rl] = s[mt][r] + SRed[rl] + vob0;
      }
  }
}

// ---------------------------------------------------------------------------
// MFMA GRU v10 (best measured: 84.9us, round 3). Parked: per-step serial
// chain (barrier+ds_read+MFMA dep+transcendental) is the floor; R1/R3/R4
// falsified barrier-drain / load-latency / CU-contention theories.
// ---------------------------------------------------------------------------
__global__ __launch_bounds__(512, 1)
void grum8_k(const ushort* __restrict__ gih, const float* __restrict__ hidden0,
             const int* __restrict__ dones, const float* __restrict__ gWh,
             const float* __restrict__ bhn, __hip_bfloat16* __restrict__ eb_out,
             float* __restrict__ hout)
{
  __shared__ ushort wstg[32*392];
  __shared__ ushort hb[2][16*136];
  __shared__ float  dnS[T_*4];
  const int tid  = threadIdx.x;
  const int lane = tid & 63, wave = tid >> 6;
  const int quad = lane >> 4, ln = lane & 15;
  const int r0   = blockIdx.x * 4;
  const int col  = wave*16 + ln;
  const int lnb  = ln & 12;

  dnS[tid] = (dones[(size_t)(tid>>2)*B_ + r0 + (tid&3)] != 0) ? 1.f : 0.f;
  const float bhnr = bhn[col];

  for (int i=tid; i<16*136; i+=512){ hb[0][i]=0; hb[1][i]=0; }

  f16x8 bf[3][4];
  #pragma unroll
  for (int kc=0; kc<4; kc++){
    for (int i=tid; i<32*384; i+=512){
      int kk = i/384, c = i - kk*384;
      wstg[kk*392 + c] = f2hu(gWh[(size_t)(kc*32+kk)*384 + c]);
    }
    __syncthreads();
    #pragma unroll
    for (int g=0; g<3; g++){
      int c = g*128 + col;
      ushort tmp[8];
      #pragma unroll
      for (int j=0;j<8;j++) tmp[j] = wstg[(quad*8+j)*392 + c];
      bf[g][kc] = *(const f16x8*)tmp;
    }
    __syncthreads();
  }

  float hc = hidden0[(size_t)(r0+quad)*D_ + col];
  if (dnS[quad] > 0.5f) hc = 0.f;
  hb[0][(quad*4)*136 + col] = f2hu(hc);
  __syncthreads();

  const ushort* gbase = gih + ((size_t)(r0+quad))*384;
  const size_t  gstep = (size_t)B_*384;

  float c_r, c_z, c_n;
  c_r = hu2f(gbase[col]); c_z = hu2f(gbase[col+128]); c_n = hu2f(gbase[col+256]);
  ushort aR,aZ,aN, bR,bZ,bN, cR,cZ,cN, dR,dZ,dN;
  { const ushort* gp = gbase + 1*gstep; aR = gp[col]; aZ = gp[col+128]; aN = gp[col+256]; }
  { const ushort* gp = gbase + 2*gstep; bR = gp[col]; bZ = gp[col+128]; bN = gp[col+256]; }
  { const ushort* gp = gbase + 3*gstep; cR = gp[col]; cZ = gp[col+128]; cN = gp[col+256]; }
  dR=0; dZ=0; dN=0;

  ushort pend_eu = 0;

#define GSTEP(t, IR,IZ,IN, OR,OZ,ON)                                          \
  {                                                                           \
    if ((t) > 0)                                                              \
      ((ushort*)eb_out)[((size_t)((t)-1)*B_ + r0+quad)*D_ + col] = pend_eu;   \
    { int tl = (t)+4; if (tl > T_-1) tl = T_-1;                               \
      const ushort* gp = gbase + (size_t)tl*gstep;                            \
      OR = gp[col]; OZ = gp[col+128]; ON = gp[col+256]; }                     \
    const ushort* hbuf = hb[(t)&1];                                           \
    f32x4 accA[3], accB[3];                                                   \
    _Pragma("unroll")                                                         \
    for (int g=0;g<3;g++){                                                    \
      _Pragma("unroll")                                                       \
      for (int r=0;r<4;r++){ accA[g][r]=0.f; accB[g][r]=0.f; }                \
    }                                                                         \
    _Pragma("unroll")                                                         \
    for (int ks=0; ks<2; ks++){                                               \
      f16x8 ahA = *(const f16x8*)&hbuf[lnb*136 + (2*ks  )*32 + quad*8];       \
      f16x8 ahB = *(const f16x8*)&hbuf[lnb*136 + (2*ks+1)*32 + quad*8];       \
      _Pragma("unroll")                                                       \
      for (int g=0;g<3;g++){                                                  \
        accA[g] = __builtin_amdgcn_mfma_f32_16x16x32_f16(ahA, bf[g][2*ks  ], accA[g], 0,0,0); \
        accB[g] = __builtin_amdgcn_mfma_f32_16x16x32_f16(ahB, bf[g][2*ks+1], accB[g], 0,0,0); \
      }                                                                       \
    }                                                                         \
    const float dnow  = dnS[(t)*4 + quad];                                    \
    const float dnext = ((t)+1 < T_) ? dnS[((t)+1)*4 + quad] : 0.f;           \
    float rg = sigmoidf_(c_r + accA[0][0] + accB[0][0]);                      \
    float zg = sigmoidf_(c_z + accA[1][0] + accB[1][0]);                      \
    float x  = c_n + rg*(accA[2][0] + accB[2][0] + bhnr);                     \
    float ng = 2.f/(1.f+__expf(-2.f*x)) - 1.f;                                \
    float hnew = (1.f - zg)*ng + zg*hc;                                       \
    pend_eu = f2bu(hnew*(1.f-dnow));                                          \
    float hv = (dnext > 0.5f) ? 0.f : hnew;                                   \
    hc = hv;                                                                  \
    hb[((t)+1)&1][(quad*4)*136 + col] = f2hu(hv);                             \
    asm volatile("s_waitcnt lgkmcnt(0)\n\ts_barrier" ::: "memory");           \
    c_r = hu2f(IR); c_z = hu2f(IZ); c_n = hu2f(IN);                           \
  }

  for (int t=0; t<T_; t+=4){
    GSTEP(t+0, aR,aZ,aN, dR,dZ,dN);
    GSTEP(t+1, bR,bZ,bN, aR,aZ,aN);
    GSTEP(t+2, cR,cZ,cN, bR,bZ,bN);
    GSTEP(t+3, dR,dZ,dN, cR,cZ,cN);
  }
#undef GSTEP

  ((ushort*)eb_out)[((size_t)(T_-1)*B_ + r0+quad)*D_ + col] = pend_eu;
  hout[(size_t)(r0+quad)*D_ + col] = hc;
}

// ---------------------------------------------------------------------------
// Weight-prep preamble.
// ---------------------------------------------------------------------------
__global__ __launch_bounds__(256)
void packall_k(const float* __restrict__ e1w, ushort* __restrict__ e1T,
               const float* __restrict__ e2w, ushort* __restrict__ e2T,
               const float* __restrict__ gWi, ushort* __restrict__ giT,
               const float* __restrict__ chw, __hip_bfloat16* __restrict__ bcatT,
               const float* __restrict__ uhw, __hip_bfloat16* __restrict__ uhwT,
               const float* __restrict__ uow, __hip_bfloat16* __restrict__ uowT,
               const float* __restrict__ v1w, __hip_bfloat16* __restrict__ v1wT,
               const float* __restrict__ v2w, __hip_bfloat16* __restrict__ v2wT)
{
  const int b = blockIdx.x, tid = threadIdx.x;
  if (b < 32){
    int idx = b*256 + tid;
    int n = idx >> 6, k = idx & 63;
    e1T[idx] = f2hu(e1w[k*128 + n]);
  } else if (b < 96){
    int idx = (b-32)*256 + tid;
    int n = idx >> 7, k = idx & 127;
    e2T[idx] = f2hu(e2w[k*128 + n]);
  } else if (b < 288){
    int idx = (b-96)*256 + tid;
    int n = idx >> 7, k = idx & 127;
    giT[idx] = f2hu(gWi[k*384 + n]);
  } else if (b < 416){
    int idx = (b-288)*256 + tid;
    int n = idx >> 7, k = idx & 127;
    float v = (n < 128) ? chw[k*128 + n] : chw[(128+k)*128 + (n-128)];
    bcatT[idx] = __float2bfloat16(v);
  } else if (b < 544){
    int idx = (b-416)*256 + tid;
    int r = idx >> 7, c = idx & 127;
    uhwT[c*256 + r] = __float2bfloat16(uhw[idx]);
  } else if (b < 608){
    int idx = (b-544)*256 + tid;
    int r = idx >> 7, c = idx & 127;
    uowT[c*128 + r] = __float2bfloat16(uow[idx]);
  } else if (b < 736){
    int idx = (b-608)*256 + tid;
    int r = idx >> 8, c = idx & 255;
    v1wT[c*128 + r] = __float2bfloat16(v1w[idx]);
  } else {
    int idx = (b-736)*256 + tid;
    int r = idx >> 8, c = idx & 255;
    v2wT[c*256 + r] = __float2bfloat16(v2w[idx]);
  }
}

extern "C" void kernel_launch(void* const* d_in, const int* in_sizes, int n_in,
                              void* d_out, int out_size, void* d_ws, size_t ws_size,
                              hipStream_t stream) {
  const float* hidden = (const float*)d_in[0];
  const float* obs    = (const float*)d_in[1];
  const int*   dones  = (const int*)  d_in[2];
  const float* e1w = (const float*)d_in[3];
  const float* e1b = (const float*)d_in[4];
  const float* e2w = (const float*)d_in[5];
  const float* e2b = (const float*)d_in[6];
  const float* gWi = (const float*)d_in[7];
  const float* gbi = (const float*)d_in[8];
  const float* gWh = (const float*)d_in[9];
  const float* gbhn= (const float*)d_in[10];
  const float* chw = (const float*)d_in[11];
  const float* chb = (const float*)d_in[12];
  const float* cow = (const float*)d_in[13];
  const float* cob = (const float*)d_in[14];
  const float* uhw = (const float*)d_in[15];
  const float* uhb = (const float*)d_in[16];
  const float* uow = (const float*)d_in[17];
  const float* uob = (const float*)d_in[18];
  const float* v1w = (const float*)d_in[19];
  const float* v1b = (const float*)d_in[20];
  const float* v2w = (const float*)d_in[21];
  const float* v2b = (const float*)d_in[22];
  const float* vow = (const float*)d_in[23];
  const float* vob = (const float*)d_in[24];
  (void)in_sizes; (void)n_in; (void)out_size;

  float* out_hidden = (float*)d_out;
  float* out_values = (float*)d_out + (size_t)B_*D_;

  // Arena (float-slot offsets).
  float* ws = (float*)d_ws;
  ushort* giH   = (ushort*)(ws + 10485760);           // [10.49M, 23.07M)
  __hip_bfloat16* Xe = (__hip_bfloat16*)(ws + 23068672); // [23.07M, 27.26M)
  ushort* wb    = (ushort*)(ws + 27262976);           // weights
  if (ws_size < (size_t)27500000 * sizeof(float)) return;

  __hip_bfloat16* bcatT = (__hip_bfloat16*)wb;           // [256][128]
  __hip_bfloat16* uhwT  = (__hip_bfloat16*)wb + 32768;   // [128][256]
  __hip_bfloat16* uowT  = (__hip_bfloat16*)wb + 65536;   // [128][128]
  __hip_bfloat16* v1wT  = (__hip_bfloat16*)wb + 81920;   // [256][128]
  __hip_bfloat16* v2wT  = (__hip_bfloat16*)wb + 114688;  // [256][256]
  ushort* e1wT = wb + 180224;   // [128][64]  fp16
  ushort* e2wT = wb + 188416;   // [128][128] fp16
  ushort* gWiT = wb + 204800;   // [384][128] fp16

  dim3 blk(256);
  packall_k<<<dim3(992), blk, 0, stream>>>(
    e1w, e1wT, e2w, e2wT, gWi, gWiT,
    chw, bcatT, uhw, uhwT, uow, uowT, v1w, v1wT, v2w, v2wT);

  // fused obs -> emb1 -> emb2 -> gi, 8 waves/block
  embgi_k<<<dim3(512), dim3(512), 0, stream>>>(obs, e1wT, e1b, e2wT, e2b, gWiT, gbi, giH);

  // MFMA GRU (best measured config)
  grum8_k<<<dim3(128), dim3(512), 0, stream>>>(giH, hidden, dones, gWh, gbhn, Xe, out_hidden);

  // whole post-GRU section (R16 config: coupling direct-L2, rest staged)
  postgru_k<<<dim3(512), dim3(512), 0, stream>>>(Xe, bcatT, chb, cow, cob,
                                                 uhwT, uhb, uowT, uob, dones,
                                                 v1wT, v1b, v2wT, v2b, vow, vob, out_values);
}